// Round 1
// baseline (11918.378 us; speedup 1.0000x reference)
//
#include <hip/hip_runtime.h>
#include <math.h>

// MoE-GPT forward, round 0: correctness-first all-f32 pipeline.
// N=4096 tokens, C=1024, H=16 heads, d=64, L=3, FF=4096, E=8 experts, V=32000.

#define NTOK  4096
#define CDIM  1024
#define HEADS 16
#define DHEAD 64
#define LAYERS 3
#define NEXP  8
#define DEXP  1024
#define TSEQ  512
#define FFDIM 4096
#define VOCAB 32000
#define C3    3072

// ---------------- embedding gather ----------------
__global__ __launch_bounds__(256) void embed_kernel(const int* __restrict__ idx,
                                                    const float* __restrict__ emb,
                                                    float* __restrict__ x) {
  int i = blockIdx.x * 256 + threadIdx.x;      // over NTOK*256 float4s
  int n = i >> 8, c4 = i & 255;
  const float4* src = (const float4*)(emb + (size_t)idx[n] * CDIM);
  ((float4*)(x + (size_t)n * CDIM))[c4] = src[c4];
}

// ---------------- RoPE cos/sin table [T][32] ----------------
__global__ void rope_table_kernel(float* __restrict__ ct, float* __restrict__ st) {
  int t = blockIdx.x, p = threadIdx.x;         // 512 x 32
  float inv = powf(10000.0f, -(float)p / 32.0f);
  float ang = (float)t * inv;
  ct[t * 32 + p] = cosf(ang);
  st[t * 32 + p] = sinf(ang);
}

// ---------------- RoPE applied in-place to q,k inside qkv [N][3*C] ----------------
__global__ __launch_bounds__(256) void rope_apply_kernel(float* __restrict__ qkv,
                                                         const float* __restrict__ ct,
                                                         const float* __restrict__ st) {
  int i = blockIdx.x * 256 + threadIdx.x;      // over NTOK*HEADS*32 pairs
  int n = i >> 9;
  int h = (i >> 5) & (HEADS - 1);
  int p = i & 31;
  int t = n & (TSEQ - 1);
  float c0 = ct[t * 32 + p], s0 = st[t * 32 + p];
  size_t base = (size_t)n * C3 + h * DHEAD;
#pragma unroll
  for (int s = 0; s < 2; s++) {                // q then k
    float* ptr = qkv + base + s * CDIM;
    float a = ptr[p], b = ptr[p + 32];
    ptr[p]      = a * c0 - b * s0;             // rot_half low  = -x2
    ptr[p + 32] = b * c0 + a * s0;             // rot_half high =  x1
  }
}

// ---------------- LayerNorm, one block per row ----------------
__global__ __launch_bounds__(256) void ln_kernel(const float* __restrict__ x,
                                                 float* __restrict__ y,
                                                 const float* __restrict__ g,
                                                 const float* __restrict__ b) {
  int n = blockIdx.x, tid = threadIdx.x;
  const float4* xr = (const float4*)(x + (size_t)n * CDIM);
  float4 v = xr[tid];
  float s = v.x + v.y + v.z + v.w;
  float ss = v.x * v.x + v.y * v.y + v.z * v.z + v.w * v.w;
  __shared__ float rs[256], rss[256];
  rs[tid] = s; rss[tid] = ss;
  __syncthreads();
  for (int o = 128; o > 0; o >>= 1) {
    if (tid < o) { rs[tid] += rs[tid + o]; rss[tid] += rss[tid + o]; }
    __syncthreads();
  }
  float m = rs[0] * (1.0f / CDIM);
  float var = rss[0] * (1.0f / CDIM) - m * m;
  float r = rsqrtf(var + 1e-5f);
  float4 gv = ((const float4*)g)[tid];
  float4 bv = ((const float4*)b)[tid];
  float4 o4;
  o4.x = (v.x - m) * r * gv.x + bv.x;
  o4.y = (v.y - m) * r * gv.y + bv.y;
  o4.z = (v.z - m) * r * gv.z + bv.z;
  o4.w = (v.w - m) * r * gv.w + bv.w;
  ((float4*)(y + (size_t)n * CDIM))[tid] = o4;
}

// ---------------- generic tiled f32 GEMM: C = act(A@B + bias), epilogues ----------------
// mode 0: store   mode 1: C += v   mode 2: C += rowscale[m]*v
// act  0: none    act  1: exact GELU
__global__ __launch_bounds__(256) void gemm_f32(const float* __restrict__ A,
                                                const float* __restrict__ B,
                                                float* __restrict__ Cmat,
                                                const float* __restrict__ bias,
                                                const float* __restrict__ rowscale,
                                                int M, int Nn, int K, int mode, int act) {
  __shared__ float As[16][68];  // [k][m], padded: row stride 272B (16B-aligned, conflict-light)
  __shared__ float Bs[16][68];  // [k][n]
  int bm = blockIdx.y * 64, bn = blockIdx.x * 64;
  int tid = threadIdx.x;
  int tx = tid & 15, ty = tid >> 4;
  float acc[4][4] = {};
  for (int k0 = 0; k0 < K; k0 += 16) {
    // A tile 64x16: thread -> row tid>>2, 4 cols
    {
      int r = tid >> 2, c4 = (tid & 3) << 2;
      float4 a4 = *(const float4*)&A[(size_t)(bm + r) * K + k0 + c4];
      As[c4 + 0][r] = a4.x; As[c4 + 1][r] = a4.y; As[c4 + 2][r] = a4.z; As[c4 + 3][r] = a4.w;
    }
    // B tile 16x64: thread -> row tid>>4, 4 cols
    {
      int r = tid >> 4, c4 = (tid & 15) << 2;
      float4 b4 = *(const float4*)&B[(size_t)(k0 + r) * Nn + bn + c4];
      *(float4*)&Bs[r][c4] = b4;
    }
    __syncthreads();
#pragma unroll
    for (int kk = 0; kk < 16; kk++) {
      float4 a4 = *(const float4*)&As[kk][ty * 4];
      float4 b4 = *(const float4*)&Bs[kk][tx * 4];
      float av[4] = {a4.x, a4.y, a4.z, a4.w};
      float bv[4] = {b4.x, b4.y, b4.z, b4.w};
#pragma unroll
      for (int i = 0; i < 4; i++)
#pragma unroll
        for (int j = 0; j < 4; j++) acc[i][j] += av[i] * bv[j];
    }
    __syncthreads();
  }
#pragma unroll
  for (int i = 0; i < 4; i++) {
    int m = bm + ty * 4 + i;
#pragma unroll
    for (int j = 0; j < 4; j++) {
      int n = bn + tx * 4 + j;
      float v = acc[i][j];
      if (bias) v += bias[n];
      if (act == 1) v = 0.5f * v * (1.0f + erff(v * 0.70710678118654752f));
      size_t ci = (size_t)m * Nn + n;
      if (mode == 0) Cmat[ci] = v;
      else if (mode == 1) Cmat[ci] += v;
      else Cmat[ci] += rowscale[m] * v;
    }
  }
}

// ---------------- causal attention, one wave per (b,h,q) ----------------
__global__ __launch_bounds__(64) void attn_kernel(const float* __restrict__ qkv,
                                                  float* __restrict__ att) {
  int q = blockIdx.x, h = blockIdx.y, b = blockIdx.z;
  int lane = threadIdx.x;
  __shared__ float qv[64];
  __shared__ float sc[512];
  const float* qrow = qkv + ((size_t)(b * TSEQ + q)) * C3 + h * DHEAD;
  qv[lane] = qrow[lane];
  __syncthreads();
  int nk = q + 1;
  float lmax = -1e30f;
  for (int k = lane; k < nk; k += 64) {
    const float* krow = qkv + ((size_t)(b * TSEQ + k)) * C3 + CDIM + h * DHEAD;
    float s = 0.0f;
#pragma unroll
    for (int dd = 0; dd < 64; dd++) s += qv[dd] * krow[dd];
    s *= 0.125f;                               // 1/sqrt(64)
    sc[k] = s;
    lmax = fmaxf(lmax, s);
  }
  for (int m = 32; m >= 1; m >>= 1) lmax = fmaxf(lmax, __shfl_xor(lmax, m));
  __syncthreads();
  float lsum = 0.0f;
  for (int k = lane; k < nk; k += 64) {
    float p = expf(sc[k] - lmax);
    sc[k] = p;
    lsum += p;
  }
  for (int m = 32; m >= 1; m >>= 1) lsum += __shfl_xor(lsum, m);
  float inv = 1.0f / lsum;
  __syncthreads();
  float accv = 0.0f;
  for (int k = 0; k < nk; k++) {
    const float* vrow = qkv + ((size_t)(b * TSEQ + k)) * C3 + 2 * CDIM + h * DHEAD;
    accv += sc[k] * vrow[lane];
  }
  att[((size_t)(b * TSEQ + q)) * CDIM + h * DHEAD + lane] = accv * inv;
}

// ---------------- router: logits -> softmax -> top2 -> renorm -> maskT [E][N] ----------------
__global__ __launch_bounds__(64) void router_kernel(const float* __restrict__ x,
                                                    const float* __restrict__ rw,
                                                    float* __restrict__ maskT) {
  int n = blockIdx.x, lane = threadIdx.x;
  const float* xr = x + (size_t)n * CDIM;
  float acc[NEXP] = {};
  for (int i = 0; i < CDIM / 64; i++) {
    int c = lane + 64 * i;
    float xv = xr[c];
    const float* r = rw + (size_t)c * NEXP;
#pragma unroll
    for (int e = 0; e < NEXP; e++) acc[e] += xv * r[e];
  }
  for (int m = 32; m >= 1; m >>= 1)
#pragma unroll
    for (int e = 0; e < NEXP; e++) acc[e] += __shfl_xor(acc[e], m);
  if (lane == 0) {
    float mx = acc[0];
#pragma unroll
    for (int e = 1; e < NEXP; e++) mx = fmaxf(mx, acc[e]);
    float p[NEXP];
#pragma unroll
    for (int e = 0; e < NEXP; e++) p[e] = expf(acc[e] - mx);
    int i1 = 0;
#pragma unroll
    for (int e = 1; e < NEXP; e++) if (p[e] > p[i1]) i1 = e;   // strict >: lowest idx wins ties
    int i2 = (i1 == 0) ? 1 : 0;
#pragma unroll
    for (int e = 0; e < NEXP; e++) if (e != i1 && p[e] > p[i2]) i2 = e;
    float denom = p[i1] + p[i2];
    float w1 = p[i1] / denom, w2 = p[i2] / denom;
#pragma unroll
    for (int e = 0; e < NEXP; e++) maskT[(size_t)e * NTOK + n] = 0.0f;
    maskT[(size_t)i1 * NTOK + n] = w1;
    maskT[(size_t)i2 * NTOK + n] = w2;
  }
}

extern "C" void kernel_launch(void* const* d_in, const int* in_sizes, int n_in,
                              void* d_out, int out_size, void* d_ws, size_t ws_size,
                              hipStream_t stream) {
  const int*   idx      = (const int*)d_in[0];
  const float* tok_emb  = (const float*)d_in[1];
  const float* ln1_g    = (const float*)d_in[2];
  const float* ln1_b    = (const float*)d_in[3];
  const float* ln2_g    = (const float*)d_in[4];
  const float* ln2_b    = (const float*)d_in[5];
  const float* qkv_w    = (const float*)d_in[6];
  const float* proj_w   = (const float*)d_in[7];
  const float* ff_w1    = (const float*)d_in[8];
  const float* ff_b1    = (const float*)d_in[9];
  const float* ff_w2    = (const float*)d_in[10];
  const float* ff_b2    = (const float*)d_in[11];
  const float* router_w = (const float*)d_in[12];
  const float* exp_w1   = (const float*)d_in[13];
  const float* exp_b1   = (const float*)d_in[14];
  const float* exp_w2   = (const float*)d_in[15];
  const float* exp_b2   = (const float*)d_in[16];
  const float* lnf_g    = (const float*)d_in[17];
  const float* lnf_b    = (const float*)d_in[18];
  const float* head_w   = (const float*)d_in[19];
  float* out = (float*)d_out;

  // workspace layout (floats); total ~42.0M floats ~= 168 MB
  float* ws   = (float*)d_ws;
  const size_t NC = (size_t)NTOK * CDIM;
  float* x    = ws;
  float* xn   = x + NC;
  float* qkv  = xn + NC;
  float* att  = qkv + (size_t)NTOK * C3;
  float* hff  = att + NC;
  float* maskT = hff + (size_t)NTOK * FFDIM;
  float* ct   = maskT + (size_t)NEXP * NTOK;
  float* st   = ct + (size_t)TSEQ * 32;
  float* moe_out = att;   // reuse: attention output buffer is free post-layers
  float* hmoe    = hff;   // reuse: FF hidden buffer is free post-layers

  embed_kernel<<<NTOK, 256, 0, stream>>>(idx, tok_emb, x);
  rope_table_kernel<<<TSEQ, 32, 0, stream>>>(ct, st);

  for (int l = 0; l < LAYERS; l++) {
    ln_kernel<<<NTOK, 256, 0, stream>>>(x, xn, ln1_g + l * CDIM, ln1_b + l * CDIM);
    gemm_f32<<<dim3(C3 / 64, NTOK / 64), 256, 0, stream>>>(
        xn, qkv_w + (size_t)l * CDIM * C3, qkv, nullptr, nullptr, NTOK, C3, CDIM, 0, 0);
    rope_apply_kernel<<<(NTOK * HEADS * 32) / 256, 256, 0, stream>>>(qkv, ct, st);
    attn_kernel<<<dim3(TSEQ, HEADS, 8), 64, 0, stream>>>(qkv, att);
    gemm_f32<<<dim3(CDIM / 64, NTOK / 64), 256, 0, stream>>>(
        att, proj_w + (size_t)l * CDIM * CDIM, x, nullptr, nullptr, NTOK, CDIM, CDIM, 1, 0);
    ln_kernel<<<NTOK, 256, 0, stream>>>(x, xn, ln2_g + l * CDIM, ln2_b + l * CDIM);
    gemm_f32<<<dim3(FFDIM / 64, NTOK / 64), 256, 0, stream>>>(
        xn, ff_w1 + (size_t)l * CDIM * FFDIM, hff, ff_b1 + (size_t)l * FFDIM, nullptr,
        NTOK, FFDIM, CDIM, 0, 1);
    gemm_f32<<<dim3(CDIM / 64, NTOK / 64), 256, 0, stream>>>(
        hff, ff_w2 + (size_t)l * FFDIM * CDIM, x, ff_b2 + (size_t)l * CDIM, nullptr,
        NTOK, CDIM, FFDIM, 1, 0);
  }

  router_kernel<<<NTOK, 64, 0, stream>>>(x, router_w, maskT);
  hipMemsetAsync(moe_out, 0, NC * sizeof(float), stream);
  for (int e = 0; e < NEXP; e++) {
    gemm_f32<<<dim3(DEXP / 64, NTOK / 64), 256, 0, stream>>>(
        x, exp_w1 + (size_t)e * CDIM * DEXP, hmoe, exp_b1 + (size_t)e * DEXP, nullptr,
        NTOK, DEXP, CDIM, 0, 1);
    gemm_f32<<<dim3(CDIM / 64, NTOK / 64), 256, 0, stream>>>(
        hmoe, exp_w2 + (size_t)e * DEXP * CDIM, moe_out, exp_b2 + (size_t)e * CDIM,
        maskT + (size_t)e * NTOK, NTOK, CDIM, DEXP, 2, 0);
  }

  ln_kernel<<<NTOK, 256, 0, stream>>>(moe_out, xn, lnf_g, lnf_b);
  gemm_f32<<<dim3(VOCAB / 64, NTOK / 64), 256, 0, stream>>>(
      xn, head_w, out, nullptr, nullptr, NTOK, VOCAB, CDIM, 0, 0);
}

// Round 4
// 8882.966 us; speedup vs baseline: 1.3417x; 1.3417x over previous
//
#include <hip/hip_runtime.h>
#include <math.h>

// MoE-GPT forward, round 3: BISECT — R0's proven f32 pipeline everywhere,
// EXCEPT the head GEMM which uses the new bf16 MFMA stack
// (ln_bf16 -> wconv_t -> gemm_bf16). Isolates the MFMA stack on one GEMM.

#define NTOK  4096
#define CDIM  1024
#define HEADS 16
#define DHEAD 64
#define LAYERS 3
#define NEXP  8
#define DEXP  1024
#define TSEQ  512
#define FFDIM 4096
#define VOCAB 32000
#define C3    3072

typedef __attribute__((ext_vector_type(8))) short short8;
typedef __attribute__((ext_vector_type(4))) float f32x4;

__device__ __forceinline__ unsigned short f2bf(float f) {
  unsigned int u = __builtin_bit_cast(unsigned int, f);
  return (unsigned short)((u + 0x7fffu + ((u >> 16) & 1u)) >> 16);  // RNE
}

// ---------------- embedding gather ----------------
__global__ __launch_bounds__(256) void embed_kernel(const int* __restrict__ idx,
                                                    const float* __restrict__ emb,
                                                    float* __restrict__ x) {
  int i = blockIdx.x * 256 + threadIdx.x;
  int n = i >> 8, c4 = i & 255;
  const float4* src = (const float4*)(emb + (size_t)idx[n] * CDIM);
  ((float4*)(x + (size_t)n * CDIM))[c4] = src[c4];
}

// ---------------- RoPE cos/sin table [T][32] ----------------
__global__ void rope_table_kernel(float* __restrict__ ct, float* __restrict__ st) {
  int t = blockIdx.x, p = threadIdx.x;
  float inv = powf(10000.0f, -(float)p / 32.0f);
  float ang = (float)t * inv;
  ct[t * 32 + p] = cosf(ang);
  st[t * 32 + p] = sinf(ang);
}

// ---------------- RoPE in-place on q,k ----------------
__global__ __launch_bounds__(256) void rope_apply_kernel(float* __restrict__ qkv,
                                                         const float* __restrict__ ct,
                                                         const float* __restrict__ st) {
  int i = blockIdx.x * 256 + threadIdx.x;
  int n = i >> 9;
  int h = (i >> 5) & (HEADS - 1);
  int p = i & 31;
  int t = n & (TSEQ - 1);
  float c0 = ct[t * 32 + p], s0 = st[t * 32 + p];
  size_t base = (size_t)n * C3 + h * DHEAD;
#pragma unroll
  for (int s = 0; s < 2; s++) {
    float* ptr = qkv + base + s * CDIM;
    float a = ptr[p], b = ptr[p + 32];
    ptr[p]      = a * c0 - b * s0;
    ptr[p + 32] = b * c0 + a * s0;
  }
}

// ---------------- LayerNorm f32 (R0 proven) ----------------
__global__ __launch_bounds__(256) void ln_kernel(const float* __restrict__ x,
                                                 float* __restrict__ y,
                                                 const float* __restrict__ g,
                                                 const float* __restrict__ b) {
  int n = blockIdx.x, tid = threadIdx.x;
  const float4* xr = (const float4*)(x + (size_t)n * CDIM);
  float4 v = xr[tid];
  float s = v.x + v.y + v.z + v.w;
  float ss = v.x * v.x + v.y * v.y + v.z * v.z + v.w * v.w;
  __shared__ float rs[256], rss[256];
  rs[tid] = s; rss[tid] = ss;
  __syncthreads();
  for (int o = 128; o > 0; o >>= 1) {
    if (tid < o) { rs[tid] += rs[tid + o]; rss[tid] += rss[tid + o]; }
    __syncthreads();
  }
  float m = rs[0] * (1.0f / CDIM);
  float var = rss[0] * (1.0f / CDIM) - m * m;
  float r = rsqrtf(var + 1e-5f);
  float4 gv = ((const float4*)g)[tid];
  float4 bv = ((const float4*)b)[tid];
  float4 o4;
  o4.x = (v.x - m) * r * gv.x + bv.x;
  o4.y = (v.y - m) * r * gv.y + bv.y;
  o4.z = (v.z - m) * r * gv.z + bv.z;
  o4.w = (v.w - m) * r * gv.w + bv.w;
  ((float4*)(y + (size_t)n * CDIM))[tid] = o4;
}

// ---------------- LayerNorm f32 -> bf16 (new, under test) ----------------
__global__ __launch_bounds__(256) void ln_bf16_kernel(const float* __restrict__ x,
                                                      unsigned short* __restrict__ y,
                                                      const float* __restrict__ g,
                                                      const float* __restrict__ b) {
  int n = blockIdx.x, tid = threadIdx.x;
  const float4* xr = (const float4*)(x + (size_t)n * CDIM);
  float4 v = xr[tid];
  float s = v.x + v.y + v.z + v.w;
  float ss = v.x * v.x + v.y * v.y + v.z * v.z + v.w * v.w;
  __shared__ float rs[256], rss[256];
  rs[tid] = s; rss[tid] = ss;
  __syncthreads();
  for (int o = 128; o > 0; o >>= 1) {
    if (tid < o) { rs[tid] += rs[tid + o]; rss[tid] += rss[tid + o]; }
    __syncthreads();
  }
  float m = rs[0] * (1.0f / CDIM);
  float var = rss[0] * (1.0f / CDIM) - m * m;
  float r = rsqrtf(var + 1e-5f);
  float4 gv = ((const float4*)g)[tid];
  float4 bv = ((const float4*)b)[tid];
  ushort4 o4;
  o4.x = f2bf((v.x - m) * r * gv.x + bv.x);
  o4.y = f2bf((v.y - m) * r * gv.y + bv.y);
  o4.z = f2bf((v.z - m) * r * gv.z + bv.z);
  o4.w = f2bf((v.w - m) * r * gv.w + bv.w);
  ((ushort4*)(y + (size_t)n * CDIM))[tid] = o4;
}

// ---------------- weight transpose+convert: f32 [K][N] -> bf16 [N][K] ----------------
__global__ __launch_bounds__(256) void wconv_t_kernel(const float* __restrict__ W,
                                                      unsigned short* __restrict__ Wt,
                                                      int K, int N) {
  __shared__ float t[32][33];
  int n0 = blockIdx.x * 32, k0 = blockIdx.y * 32;
  int tx = threadIdx.x & 31, ty = threadIdx.x >> 5;   // 32 x 8
#pragma unroll
  for (int i = 0; i < 4; i++)
    t[ty + 8 * i][tx] = W[(size_t)(k0 + ty + 8 * i) * N + n0 + tx];
  __syncthreads();
#pragma unroll
  for (int i = 0; i < 4; i++)
    Wt[(size_t)(n0 + ty + 8 * i) * K + k0 + tx] = f2bf(t[tx][ty + 8 * i]);
}

// ---------------- bf16 MFMA GEMM (under test), 128x128, reg-staged LDS ----------------
// C[M][N] = A[M][K] @ Bt[N][K]^T, f32 store
__global__ __launch_bounds__(256) void gemm_bf16(const unsigned short* __restrict__ A,
                                                 const unsigned short* __restrict__ Bt,
                                                 float* __restrict__ C,
                                                 int M, int Nn, int K) {
  __shared__ __align__(16) unsigned short As[128 * 32];
  __shared__ __align__(16) unsigned short Bs[128 * 32];
  const int tid = threadIdx.x;
  const int wv = tid >> 6, ln = tid & 63;
  const int bm = blockIdx.y * 128, bn = blockIdx.x * 128;

  const size_t aoff0 = (size_t)(bm + 32 * wv + (ln >> 2)) * K + (size_t)((ln & 3) * 8);
  const size_t aoff1 = aoff0 + (size_t)16 * K;
  const size_t boff0 = (size_t)(bn + 32 * wv + (ln >> 2)) * K + (size_t)((ln & 3) * 8);
  const size_t boff1 = boff0 + (size_t)16 * K;
  const int lofs = 1024 * wv + ln * 8;

  const int wm = wv >> 1, wn = wv & 1;
  const int lr = ln & 15, lg = ln >> 4;

  f32x4 acc[4][4];
#pragma unroll
  for (int i = 0; i < 4; i++)
#pragma unroll
    for (int j = 0; j < 4; j++) acc[i][j] = (f32x4){0.f, 0.f, 0.f, 0.f};

  for (int k0 = 0; k0 < K; k0 += 32) {
    short8 ra0 = *(const short8*)(A + aoff0 + k0);
    short8 ra1 = *(const short8*)(A + aoff1 + k0);
    short8 rb0 = *(const short8*)(Bt + boff0 + k0);
    short8 rb1 = *(const short8*)(Bt + boff1 + k0);
    __syncthreads();
    *(short8*)(As + lofs)       = ra0;
    *(short8*)(As + lofs + 512) = ra1;
    *(short8*)(Bs + lofs)       = rb0;
    *(short8*)(Bs + lofs + 512) = rb1;
    __syncthreads();

    short8 af[4], bw[4];
#pragma unroll
    for (int i = 0; i < 4; i++)
      af[i] = *(const short8*)(As + ((64 * wm + 16 * i + lr) * 32 + 8 * lg));
#pragma unroll
    for (int j = 0; j < 4; j++)
      bw[j] = *(const short8*)(Bs + ((64 * wn + 16 * j + lr) * 32 + 8 * lg));
#pragma unroll
    for (int i = 0; i < 4; i++)
#pragma unroll
      for (int j = 0; j < 4; j++)
        acc[i][j] = __builtin_amdgcn_mfma_f32_16x16x32_bf16(af[i], bw[j], acc[i][j], 0, 0, 0);
  }

#pragma unroll
  for (int j = 0; j < 4; j++) {
    const int n = bn + 64 * wn + 16 * j + lr;
#pragma unroll
    for (int i = 0; i < 4; i++) {
#pragma unroll
      for (int r = 0; r < 4; r++) {
        const int m = bm + 64 * wm + 16 * i + 4 * lg + r;
        C[(size_t)m * Nn + n] = acc[i][j][r];
      }
    }
  }
}

// ---------------- generic tiled f32 GEMM (R0 proven) ----------------
__global__ __launch_bounds__(256) void gemm_f32(const float* __restrict__ A,
                                                const float* __restrict__ B,
                                                float* __restrict__ Cmat,
                                                const float* __restrict__ bias,
                                                const float* __restrict__ rowscale,
                                                int M, int Nn, int K, int mode, int act) {
  __shared__ float As[16][68];
  __shared__ float Bs[16][68];
  int bm = blockIdx.y * 64, bn = blockIdx.x * 64;
  int tid = threadIdx.x;
  int tx = tid & 15, ty = tid >> 4;
  float acc[4][4] = {};
  for (int k0 = 0; k0 < K; k0 += 16) {
    {
      int r = tid >> 2, c4 = (tid & 3) << 2;
      float4 a4 = *(const float4*)&A[(size_t)(bm + r) * K + k0 + c4];
      As[c4 + 0][r] = a4.x; As[c4 + 1][r] = a4.y; As[c4 + 2][r] = a4.z; As[c4 + 3][r] = a4.w;
    }
    {
      int r = tid >> 4, c4 = (tid & 15) << 2;
      float4 b4 = *(const float4*)&B[(size_t)(k0 + r) * Nn + bn + c4];
      *(float4*)&Bs[r][c4] = b4;
    }
    __syncthreads();
#pragma unroll
    for (int kk = 0; kk < 16; kk++) {
      float4 a4 = *(const float4*)&As[kk][ty * 4];
      float4 b4 = *(const float4*)&Bs[kk][tx * 4];
      float av[4] = {a4.x, a4.y, a4.z, a4.w};
      float bv[4] = {b4.x, b4.y, b4.z, b4.w};
#pragma unroll
      for (int i = 0; i < 4; i++)
#pragma unroll
        for (int j = 0; j < 4; j++) acc[i][j] += av[i] * bv[j];
    }
    __syncthreads();
  }
#pragma unroll
  for (int i = 0; i < 4; i++) {
    int m = bm + ty * 4 + i;
#pragma unroll
    for (int j = 0; j < 4; j++) {
      int n = bn + tx * 4 + j;
      float v = acc[i][j];
      if (bias) v += bias[n];
      if (act == 1) v = 0.5f * v * (1.0f + erff(v * 0.70710678118654752f));
      size_t ci = (size_t)m * Nn + n;
      if (mode == 0) Cmat[ci] = v;
      else if (mode == 1) Cmat[ci] += v;
      else Cmat[ci] += rowscale[m] * v;
    }
  }
}

// ---------------- causal attention f32 (R0 proven) ----------------
__global__ __launch_bounds__(64) void attn_kernel(const float* __restrict__ qkv,
                                                  float* __restrict__ att) {
  int q = blockIdx.x, h = blockIdx.y, b = blockIdx.z;
  int lane = threadIdx.x;
  __shared__ float qv[64];
  __shared__ float sc[512];
  const float* qrow = qkv + ((size_t)(b * TSEQ + q)) * C3 + h * DHEAD;
  qv[lane] = qrow[lane];
  __syncthreads();
  int nk = q + 1;
  float lmax = -1e30f;
  for (int k = lane; k < nk; k += 64) {
    const float* krow = qkv + ((size_t)(b * TSEQ + k)) * C3 + CDIM + h * DHEAD;
    float s = 0.0f;
#pragma unroll
    for (int dd = 0; dd < 64; dd++) s += qv[dd] * krow[dd];
    s *= 0.125f;
    sc[k] = s;
    lmax = fmaxf(lmax, s);
  }
  for (int m = 32; m >= 1; m >>= 1) lmax = fmaxf(lmax, __shfl_xor(lmax, m));
  __syncthreads();
  float lsum = 0.0f;
  for (int k = lane; k < nk; k += 64) {
    float p = expf(sc[k] - lmax);
    sc[k] = p;
    lsum += p;
  }
  for (int m = 32; m >= 1; m >>= 1) lsum += __shfl_xor(lsum, m);
  float inv = 1.0f / lsum;
  __syncthreads();
  float accv = 0.0f;
  for (int k = 0; k < nk; k++) {
    const float* vrow = qkv + ((size_t)(b * TSEQ + k)) * C3 + 2 * CDIM + h * DHEAD;
    accv += sc[k] * vrow[lane];
  }
  att[((size_t)(b * TSEQ + q)) * CDIM + h * DHEAD + lane] = accv * inv;
}

// ---------------- router (R0 proven) ----------------
__global__ __launch_bounds__(64) void router_kernel(const float* __restrict__ x,
                                                    const float* __restrict__ rw,
                                                    float* __restrict__ maskT) {
  int n = blockIdx.x, lane = threadIdx.x;
  const float* xr = x + (size_t)n * CDIM;
  float acc[NEXP] = {};
  for (int i = 0; i < CDIM / 64; i++) {
    int c = lane + 64 * i;
    float xv = xr[c];
    const float* r = rw + (size_t)c * NEXP;
#pragma unroll
    for (int e = 0; e < NEXP; e++) acc[e] += xv * r[e];
  }
  for (int m = 32; m >= 1; m >>= 1)
#pragma unroll
    for (int e = 0; e < NEXP; e++) acc[e] += __shfl_xor(acc[e], m);
  if (lane == 0) {
    float mx = acc[0];
#pragma unroll
    for (int e = 1; e < NEXP; e++) mx = fmaxf(mx, acc[e]);
    float p[NEXP];
#pragma unroll
    for (int e = 0; e < NEXP; e++) p[e] = expf(acc[e] - mx);
    int i1 = 0;
#pragma unroll
    for (int e = 1; e < NEXP; e++) if (p[e] > p[i1]) i1 = e;
    int i2 = (i1 == 0) ? 1 : 0;
#pragma unroll
    for (int e = 0; e < NEXP; e++) if (e != i1 && p[e] > p[i2]) i2 = e;
    float denom = p[i1] + p[i2];
    float w1 = p[i1] / denom, w2 = p[i2] / denom;
#pragma unroll
    for (int e = 0; e < NEXP; e++) maskT[(size_t)e * NTOK + n] = 0.0f;
    maskT[(size_t)i1 * NTOK + n] = w1;
    maskT[(size_t)i2 * NTOK + n] = w2;
  }
}

extern "C" void kernel_launch(void* const* d_in, const int* in_sizes, int n_in,
                              void* d_out, int out_size, void* d_ws, size_t ws_size,
                              hipStream_t stream) {
  const int*   idx      = (const int*)d_in[0];
  const float* tok_emb  = (const float*)d_in[1];
  const float* ln1_g    = (const float*)d_in[2];
  const float* ln1_b    = (const float*)d_in[3];
  const float* ln2_g    = (const float*)d_in[4];
  const float* ln2_b    = (const float*)d_in[5];
  const float* qkv_w    = (const float*)d_in[6];
  const float* proj_w   = (const float*)d_in[7];
  const float* ff_w1    = (const float*)d_in[8];
  const float* ff_b1    = (const float*)d_in[9];
  const float* ff_w2    = (const float*)d_in[10];
  const float* ff_b2    = (const float*)d_in[11];
  const float* router_w = (const float*)d_in[12];
  const float* exp_w1   = (const float*)d_in[13];
  const float* exp_b1   = (const float*)d_in[14];
  const float* exp_w2   = (const float*)d_in[15];
  const float* exp_b2   = (const float*)d_in[16];
  const float* lnf_g    = (const float*)d_in[17];
  const float* lnf_b    = (const float*)d_in[18];
  const float* head_w   = (const float*)d_in[19];
  float* out = (float*)d_out;

  // workspace layout IDENTICAL to round-0 (proven ~168 MB)
  float* ws   = (float*)d_ws;
  const size_t NC = (size_t)NTOK * CDIM;
  float* x    = ws;
  float* xn   = x + NC;
  float* qkv  = xn + NC;
  float* att  = qkv + (size_t)NTOK * C3;
  float* hff  = att + NC;
  float* maskT = hff + (size_t)NTOK * FFDIM;
  float* ct   = maskT + (size_t)NEXP * NTOK;
  float* st   = ct + (size_t)TSEQ * 32;
  float* moe_out = att;   // reuse post-layers
  float* hmoe    = hff;   // reuse post-layers
  // head-phase aliases (qkv and hff dead by then):
  unsigned short* xn_bf = (unsigned short*)qkv;     // 8.4 MB needed, 50 MB avail
  unsigned short* wt    = (unsigned short*)hff;     // 65.5 MB needed, 67.1 MB avail

  embed_kernel<<<NTOK, 256, 0, stream>>>(idx, tok_emb, x);
  rope_table_kernel<<<TSEQ, 32, 0, stream>>>(ct, st);

  for (int l = 0; l < LAYERS; l++) {
    ln_kernel<<<NTOK, 256, 0, stream>>>(x, xn, ln1_g + l * CDIM, ln1_b + l * CDIM);
    gemm_f32<<<dim3(C3 / 64, NTOK / 64), 256, 0, stream>>>(
        xn, qkv_w + (size_t)l * CDIM * C3, qkv, nullptr, nullptr, NTOK, C3, CDIM, 0, 0);
    rope_apply_kernel<<<(NTOK * HEADS * 32) / 256, 256, 0, stream>>>(qkv, ct, st);
    attn_kernel<<<dim3(TSEQ, HEADS, 8), 64, 0, stream>>>(qkv, att);
    gemm_f32<<<dim3(CDIM / 64, NTOK / 64), 256, 0, stream>>>(
        att, proj_w + (size_t)l * CDIM * CDIM, x, nullptr, nullptr, NTOK, CDIM, CDIM, 1, 0);
    ln_kernel<<<NTOK, 256, 0, stream>>>(x, xn, ln2_g + l * CDIM, ln2_b + l * CDIM);
    gemm_f32<<<dim3(FFDIM / 64, NTOK / 64), 256, 0, stream>>>(
        xn, ff_w1 + (size_t)l * CDIM * FFDIM, hff, ff_b1 + (size_t)l * FFDIM, nullptr,
        NTOK, FFDIM, CDIM, 0, 1);
    gemm_f32<<<dim3(CDIM / 64, NTOK / 64), 256, 0, stream>>>(
        hff, ff_w2 + (size_t)l * FFDIM * CDIM, x, ff_b2 + (size_t)l * CDIM, nullptr,
        NTOK, CDIM, FFDIM, 1, 0);
  }

  router_kernel<<<NTOK, 64, 0, stream>>>(x, router_w, maskT);
  hipMemsetAsync(moe_out, 0, NC * sizeof(float), stream);
  for (int e = 0; e < NEXP; e++) {
    gemm_f32<<<dim3(DEXP / 64, NTOK / 64), 256, 0, stream>>>(
        x, exp_w1 + (size_t)e * CDIM * DEXP, hmoe, exp_b1 + (size_t)e * DEXP, nullptr,
        NTOK, DEXP, CDIM, 0, 1);
    gemm_f32<<<dim3(CDIM / 64, NTOK / 64), 256, 0, stream>>>(
        hmoe, exp_w2 + (size_t)e * DEXP * CDIM, moe_out, exp_b2 + (size_t)e * CDIM,
        maskT + (size_t)e * NTOK, NTOK, CDIM, DEXP, 2, 0);
  }

  // ---- head: bf16 MFMA stack under test ----
  ln_bf16_kernel<<<NTOK, 256, 0, stream>>>(moe_out, xn_bf, lnf_g, lnf_b);
  wconv_t_kernel<<<dim3(VOCAB / 32, CDIM / 32), 256, 0, stream>>>(head_w, wt, CDIM, VOCAB);
  gemm_bf16<<<dim3(VOCAB / 128, NTOK / 128), 256, 0, stream>>>(
      xn_bf, wt, out, NTOK, VOCAB, CDIM);
}

// Round 7
// 7436.890 us; speedup vs baseline: 1.6026x; 1.1944x over previous
//
#include <hip/hip_runtime.h>
#include <math.h>

// MoE-GPT forward, round 7: ROUTING-PRECISION theory test.
// Trunk (embed + 3 layers: qkv/attn/proj/FF) = R0-proven f32 (router sees
// bit-identical x). MoE experts + head = bf16 MFMA (downstream of routing,
// continuous). If this passes, trunk goes split-bf16 next round.

#define NTOK  4096
#define CDIM  1024
#define HEADS 16
#define DHEAD 64
#define LAYERS 3
#define NEXP  8
#define DEXP  1024
#define TSEQ  512
#define FFDIM 4096
#define VOCAB 32000
#define C3    3072

typedef __attribute__((ext_vector_type(8))) short short8;
typedef __attribute__((ext_vector_type(4))) float f32x4;

__device__ __forceinline__ unsigned short f2bf(float f) {
  unsigned int u = __builtin_bit_cast(unsigned int, f);
  return (unsigned short)((u + 0x7fffu + ((u >> 16) & 1u)) >> 16);  // RNE
}

// ---------------- embedding gather ----------------
__global__ __launch_bounds__(256) void embed_kernel(const int* __restrict__ idx,
                                                    const float* __restrict__ emb,
                                                    float* __restrict__ x) {
  int i = blockIdx.x * 256 + threadIdx.x;
  int n = i >> 8, c4 = i & 255;
  const float4* src = (const float4*)(emb + (size_t)idx[n] * CDIM);
  ((float4*)(x + (size_t)n * CDIM))[c4] = src[c4];
}

// ---------------- RoPE cos/sin table [T][32] ----------------
__global__ void rope_table_kernel(float* __restrict__ ct, float* __restrict__ st) {
  int t = blockIdx.x, p = threadIdx.x;
  float inv = powf(10000.0f, -(float)p / 32.0f);
  float ang = (float)t * inv;
  ct[t * 32 + p] = cosf(ang);
  st[t * 32 + p] = sinf(ang);
}

// ---------------- RoPE in-place on q,k ----------------
__global__ __launch_bounds__(256) void rope_apply_kernel(float* __restrict__ qkv,
                                                         const float* __restrict__ ct,
                                                         const float* __restrict__ st) {
  int i = blockIdx.x * 256 + threadIdx.x;
  int n = i >> 9;
  int h = (i >> 5) & (HEADS - 1);
  int p = i & 31;
  int t = n & (TSEQ - 1);
  float c0 = ct[t * 32 + p], s0 = st[t * 32 + p];
  size_t base = (size_t)n * C3 + h * DHEAD;
#pragma unroll
  for (int s = 0; s < 2; s++) {
    float* ptr = qkv + base + s * CDIM;
    float a = ptr[p], b = ptr[p + 32];
    ptr[p]      = a * c0 - b * s0;
    ptr[p + 32] = b * c0 + a * s0;
  }
}

// ---------------- LayerNorm f32 (R0 proven) ----------------
__global__ __launch_bounds__(256) void ln_kernel(const float* __restrict__ x,
                                                 float* __restrict__ y,
                                                 const float* __restrict__ g,
                                                 const float* __restrict__ b) {
  int n = blockIdx.x, tid = threadIdx.x;
  const float4* xr = (const float4*)(x + (size_t)n * CDIM);
  float4 v = xr[tid];
  float s = v.x + v.y + v.z + v.w;
  float ss = v.x * v.x + v.y * v.y + v.z * v.z + v.w * v.w;
  __shared__ float rs[256], rss[256];
  rs[tid] = s; rss[tid] = ss;
  __syncthreads();
  for (int o = 128; o > 0; o >>= 1) {
    if (tid < o) { rs[tid] += rs[tid + o]; rss[tid] += rss[tid + o]; }
    __syncthreads();
  }
  float m = rs[0] * (1.0f / CDIM);
  float var = rss[0] * (1.0f / CDIM) - m * m;
  float r = rsqrtf(var + 1e-5f);
  float4 gv = ((const float4*)g)[tid];
  float4 bv = ((const float4*)b)[tid];
  float4 o4;
  o4.x = (v.x - m) * r * gv.x + bv.x;
  o4.y = (v.y - m) * r * gv.y + bv.y;
  o4.z = (v.z - m) * r * gv.z + bv.z;
  o4.w = (v.w - m) * r * gv.w + bv.w;
  ((float4*)(y + (size_t)n * CDIM))[tid] = o4;
}

// ---------------- LayerNorm f32 -> bf16 (R4 proven) ----------------
__global__ __launch_bounds__(256) void ln_bf16_kernel(const float* __restrict__ x,
                                                      unsigned short* __restrict__ y,
                                                      const float* __restrict__ g,
                                                      const float* __restrict__ b) {
  int n = blockIdx.x, tid = threadIdx.x;
  const float4* xr = (const float4*)(x + (size_t)n * CDIM);
  float4 v = xr[tid];
  float s = v.x + v.y + v.z + v.w;
  float ss = v.x * v.x + v.y * v.y + v.z * v.z + v.w * v.w;
  __shared__ float rs[256], rss[256];
  rs[tid] = s; rss[tid] = ss;
  __syncthreads();
  for (int o = 128; o > 0; o >>= 1) {
    if (tid < o) { rs[tid] += rs[tid + o]; rss[tid] += rss[tid + o]; }
    __syncthreads();
  }
  float m = rs[0] * (1.0f / CDIM);
  float var = rss[0] * (1.0f / CDIM) - m * m;
  float r = rsqrtf(var + 1e-5f);
  float4 gv = ((const float4*)g)[tid];
  float4 bv = ((const float4*)b)[tid];
  ushort4 o4;
  o4.x = f2bf((v.x - m) * r * gv.x + bv.x);
  o4.y = f2bf((v.y - m) * r * gv.y + bv.y);
  o4.z = f2bf((v.z - m) * r * gv.z + bv.z);
  o4.w = f2bf((v.w - m) * r * gv.w + bv.w);
  ((ushort4*)(y + (size_t)n * CDIM))[tid] = o4;
}

// ---------------- f32 -> bf16 convert ----------------
__global__ __launch_bounds__(256) void cvt_bf16_kernel(const float* __restrict__ x,
                                                       unsigned short* __restrict__ y) {
  int i = blockIdx.x * 256 + threadIdx.x;
  float4 v = ((const float4*)x)[i];
  ushort4 o;
  o.x = f2bf(v.x); o.y = f2bf(v.y); o.z = f2bf(v.z); o.w = f2bf(v.w);
  ((ushort4*)y)[i] = o;
}

// ---------------- elementwise: out_bf16 = gelu(in + bias[col]) ----------------
__global__ __launch_bounds__(256) void biasgelu_cvt_kernel(const float* __restrict__ in,
                                                           const float* __restrict__ bias,
                                                           unsigned short* __restrict__ out,
                                                           int Fm4) {
  int i = blockIdx.x * 256 + threadIdx.x;
  int c4 = (i & (Fm4 - 1)) << 2;
  float4 v = ((const float4*)in)[i];
  float4 b = *(const float4*)(bias + c4);
  float a0 = v.x + b.x, a1 = v.y + b.y, a2 = v.z + b.z, a3 = v.w + b.w;
  ushort4 o;
  o.x = f2bf(0.5f * a0 * (1.0f + erff(a0 * 0.70710678118654752f)));
  o.y = f2bf(0.5f * a1 * (1.0f + erff(a1 * 0.70710678118654752f)));
  o.z = f2bf(0.5f * a2 * (1.0f + erff(a2 * 0.70710678118654752f)));
  o.w = f2bf(0.5f * a3 * (1.0f + erff(a3 * 0.70710678118654752f)));
  ((ushort4*)out)[i] = o;
}

// ---------------- elementwise: o += rs[row] * (t + bias[col]) (F = CDIM) ----------------
__global__ __launch_bounds__(256) void scaleadd_kernel(float* __restrict__ o,
                                                       const float* __restrict__ t,
                                                       const float* __restrict__ bias,
                                                       const float* __restrict__ rs) {
  int i = blockIdx.x * 256 + threadIdx.x;
  int m = i >> 8;                         // i / (CDIM/4)
  int c4 = (i & (CDIM / 4 - 1)) << 2;
  float w = rs[m];
  float4 ov = ((const float4*)o)[i];
  float4 tv = ((const float4*)t)[i];
  float4 b = *(const float4*)(bias + c4);
  ov.x += w * (tv.x + b.x); ov.y += w * (tv.y + b.y);
  ov.z += w * (tv.z + b.z); ov.w += w * (tv.w + b.w);
  ((float4*)o)[i] = ov;
}

// ---------------- weight transpose+convert (R4 proven) ----------------
__global__ __launch_bounds__(256) void wconv_t_kernel(const float* __restrict__ W,
                                                      unsigned short* __restrict__ Wt,
                                                      int K, int N) {
  __shared__ float t[32][33];
  int n0 = blockIdx.x * 32, k0 = blockIdx.y * 32;
  int tx = threadIdx.x & 31, ty = threadIdx.x >> 5;   // 32 x 8
#pragma unroll
  for (int i = 0; i < 4; i++)
    t[ty + 8 * i][tx] = W[(size_t)(k0 + ty + 8 * i) * N + n0 + tx];
  __syncthreads();
#pragma unroll
  for (int i = 0; i < 4; i++)
    Wt[(size_t)(n0 + ty + 8 * i) * K + k0 + tx] = f2bf(t[tx][ty + 8 * i]);
}

// ---------------- bf16 MFMA GEMM (R4 proven config) ----------------
// C[M][N] = A[M][K] @ Bt[N][K]^T, f32 store
__global__ __launch_bounds__(256) void gemm_bf16(const unsigned short* __restrict__ A,
                                                 const unsigned short* __restrict__ Bt,
                                                 float* __restrict__ C,
                                                 int M, int Nn, int K) {
  __shared__ __align__(16) unsigned short As[128 * 32];
  __shared__ __align__(16) unsigned short Bs[128 * 32];
  const int tid = threadIdx.x;
  const int wv = tid >> 6, ln = tid & 63;
  const int bm = blockIdx.y * 128, bn = blockIdx.x * 128;

  const size_t aoff0 = (size_t)(bm + 32 * wv + (ln >> 2)) * K + (size_t)((ln & 3) * 8);
  const size_t aoff1 = aoff0 + (size_t)16 * K;
  const size_t boff0 = (size_t)(bn + 32 * wv + (ln >> 2)) * K + (size_t)((ln & 3) * 8);
  const size_t boff1 = boff0 + (size_t)16 * K;
  const int lofs = 1024 * wv + ln * 8;

  const int wm = wv >> 1, wn = wv & 1;
  const int lr = ln & 15, lg = ln >> 4;

  f32x4 acc[4][4];
#pragma unroll
  for (int i = 0; i < 4; i++)
#pragma unroll
    for (int j = 0; j < 4; j++) acc[i][j] = (f32x4){0.f, 0.f, 0.f, 0.f};

  for (int k0 = 0; k0 < K; k0 += 32) {
    short8 ra0 = *(const short8*)(A + aoff0 + k0);
    short8 ra1 = *(const short8*)(A + aoff1 + k0);
    short8 rb0 = *(const short8*)(Bt + boff0 + k0);
    short8 rb1 = *(const short8*)(Bt + boff1 + k0);
    __syncthreads();
    *(short8*)(As + lofs)       = ra0;
    *(short8*)(As + lofs + 512) = ra1;
    *(short8*)(Bs + lofs)       = rb0;
    *(short8*)(Bs + lofs + 512) = rb1;
    __syncthreads();

    short8 af[4], bw[4];
#pragma unroll
    for (int i = 0; i < 4; i++)
      af[i] = *(const short8*)(As + ((64 * wm + 16 * i + lr) * 32 + 8 * lg));
#pragma unroll
    for (int j = 0; j < 4; j++)
      bw[j] = *(const short8*)(Bs + ((64 * wn + 16 * j + lr) * 32 + 8 * lg));
#pragma unroll
    for (int i = 0; i < 4; i++)
#pragma unroll
      for (int j = 0; j < 4; j++)
        acc[i][j] = __builtin_amdgcn_mfma_f32_16x16x32_bf16(af[i], bw[j], acc[i][j], 0, 0, 0);
  }

#pragma unroll
  for (int j = 0; j < 4; j++) {
    const int n = bn + 64 * wn + 16 * j + lr;
#pragma unroll
    for (int i = 0; i < 4; i++) {
#pragma unroll
      for (int r = 0; r < 4; r++) {
        const int m = bm + 64 * wm + 16 * i + 4 * lg + r;
        C[(size_t)m * Nn + n] = acc[i][j][r];
      }
    }
  }
}

// ---------------- generic tiled f32 GEMM (R0 proven) ----------------
__global__ __launch_bounds__(256) void gemm_f32(const float* __restrict__ A,
                                                const float* __restrict__ B,
                                                float* __restrict__ Cmat,
                                                const float* __restrict__ bias,
                                                const float* __restrict__ rowscale,
                                                int M, int Nn, int K, int mode, int act) {
  __shared__ float As[16][68];
  __shared__ float Bs[16][68];
  int bm = blockIdx.y * 64, bn = blockIdx.x * 64;
  int tid = threadIdx.x;
  int tx = tid & 15, ty = tid >> 4;
  float acc[4][4] = {};
  for (int k0 = 0; k0 < K; k0 += 16) {
    {
      int r = tid >> 2, c4 = (tid & 3) << 2;
      float4 a4 = *(const float4*)&A[(size_t)(bm + r) * K + k0 + c4];
      As[c4 + 0][r] = a4.x; As[c4 + 1][r] = a4.y; As[c4 + 2][r] = a4.z; As[c4 + 3][r] = a4.w;
    }
    {
      int r = tid >> 4, c4 = (tid & 15) << 2;
      float4 b4 = *(const float4*)&B[(size_t)(k0 + r) * Nn + bn + c4];
      *(float4*)&Bs[r][c4] = b4;
    }
    __syncthreads();
#pragma unroll
    for (int kk = 0; kk < 16; kk++) {
      float4 a4 = *(const float4*)&As[kk][ty * 4];
      float4 b4 = *(const float4*)&Bs[kk][tx * 4];
      float av[4] = {a4.x, a4.y, a4.z, a4.w};
      float bv[4] = {b4.x, b4.y, b4.z, b4.w};
#pragma unroll
      for (int i = 0; i < 4; i++)
#pragma unroll
        for (int j = 0; j < 4; j++) acc[i][j] += av[i] * bv[j];
    }
    __syncthreads();
  }
#pragma unroll
  for (int i = 0; i < 4; i++) {
    int m = bm + ty * 4 + i;
#pragma unroll
    for (int j = 0; j < 4; j++) {
      int n = bn + tx * 4 + j;
      float v = acc[i][j];
      if (bias) v += bias[n];
      if (act == 1) v = 0.5f * v * (1.0f + erff(v * 0.70710678118654752f));
      size_t ci = (size_t)m * Nn + n;
      if (mode == 0) Cmat[ci] = v;
      else if (mode == 1) Cmat[ci] += v;
      else Cmat[ci] += rowscale[m] * v;
    }
  }
}

// ---------------- causal attention f32 (R0 proven) ----------------
__global__ __launch_bounds__(64) void attn_kernel(const float* __restrict__ qkv,
                                                  float* __restrict__ att) {
  int q = blockIdx.x, h = blockIdx.y, b = blockIdx.z;
  int lane = threadIdx.x;
  __shared__ float qv[64];
  __shared__ float sc[512];
  const float* qrow = qkv + ((size_t)(b * TSEQ + q)) * C3 + h * DHEAD;
  qv[lane] = qrow[lane];
  __syncthreads();
  int nk = q + 1;
  float lmax = -1e30f;
  for (int k = lane; k < nk; k += 64) {
    const float* krow = qkv + ((size_t)(b * TSEQ + k)) * C3 + CDIM + h * DHEAD;
    float s = 0.0f;
#pragma unroll
    for (int dd = 0; dd < 64; dd++) s += qv[dd] * krow[dd];
    s *= 0.125f;
    sc[k] = s;
    lmax = fmaxf(lmax, s);
  }
  for (int m = 32; m >= 1; m >>= 1) lmax = fmaxf(lmax, __shfl_xor(lmax, m));
  __syncthreads();
  float lsum = 0.0f;
  for (int k = lane; k < nk; k += 64) {
    float p = expf(sc[k] - lmax);
    sc[k] = p;
    lsum += p;
  }
  for (int m = 32; m >= 1; m >>= 1) lsum += __shfl_xor(lsum, m);
  float inv = 1.0f / lsum;
  __syncthreads();
  float accv = 0.0f;
  for (int k = 0; k < nk; k++) {
    const float* vrow = qkv + ((size_t)(b * TSEQ + k)) * C3 + 2 * CDIM + h * DHEAD;
    accv += sc[k] * vrow[lane];
  }
  att[((size_t)(b * TSEQ + q)) * CDIM + h * DHEAD + lane] = accv * inv;
}

// ---------------- router (R0 proven) ----------------
__global__ __launch_bounds__(64) void router_kernel(const float* __restrict__ x,
                                                    const float* __restrict__ rw,
                                                    float* __restrict__ maskT) {
  int n = blockIdx.x, lane = threadIdx.x;
  const float* xr = x + (size_t)n * CDIM;
  float acc[NEXP] = {};
  for (int i = 0; i < CDIM / 64; i++) {
    int c = lane + 64 * i;
    float xv = xr[c];
    const float* r = rw + (size_t)c * NEXP;
#pragma unroll
    for (int e = 0; e < NEXP; e++) acc[e] += xv * r[e];
  }
  for (int m = 32; m >= 1; m >>= 1)
#pragma unroll
    for (int e = 0; e < NEXP; e++) acc[e] += __shfl_xor(acc[e], m);
  if (lane == 0) {
    float mx = acc[0];
#pragma unroll
    for (int e = 1; e < NEXP; e++) mx = fmaxf(mx, acc[e]);
    float p[NEXP];
#pragma unroll
    for (int e = 0; e < NEXP; e++) p[e] = expf(acc[e] - mx);
    int i1 = 0;
#pragma unroll
    for (int e = 1; e < NEXP; e++) if (p[e] > p[i1]) i1 = e;
    int i2 = (i1 == 0) ? 1 : 0;
#pragma unroll
    for (int e = 0; e < NEXP; e++) if (e != i1 && p[e] > p[i2]) i2 = e;
    float denom = p[i1] + p[i2];
    float w1 = p[i1] / denom, w2 = p[i2] / denom;
#pragma unroll
    for (int e = 0; e < NEXP; e++) maskT[(size_t)e * NTOK + n] = 0.0f;
    maskT[(size_t)i1 * NTOK + n] = w1;
    maskT[(size_t)i2 * NTOK + n] = w2;
  }
}

extern "C" void kernel_launch(void* const* d_in, const int* in_sizes, int n_in,
                              void* d_out, int out_size, void* d_ws, size_t ws_size,
                              hipStream_t stream) {
  const int*   idx      = (const int*)d_in[0];
  const float* tok_emb  = (const float*)d_in[1];
  const float* ln1_g    = (const float*)d_in[2];
  const float* ln1_b    = (const float*)d_in[3];
  const float* ln2_g    = (const float*)d_in[4];
  const float* ln2_b    = (const float*)d_in[5];
  const float* qkv_w    = (const float*)d_in[6];
  const float* proj_w   = (const float*)d_in[7];
  const float* ff_w1    = (const float*)d_in[8];
  const float* ff_b1    = (const float*)d_in[9];
  const float* ff_w2    = (const float*)d_in[10];
  const float* ff_b2    = (const float*)d_in[11];
  const float* router_w = (const float*)d_in[12];
  const float* exp_w1   = (const float*)d_in[13];
  const float* exp_b1   = (const float*)d_in[14];
  const float* exp_w2   = (const float*)d_in[15];
  const float* exp_b2   = (const float*)d_in[16];
  const float* lnf_g    = (const float*)d_in[17];
  const float* lnf_b    = (const float*)d_in[18];
  const float* head_w   = (const float*)d_in[19];
  float* out = (float*)d_out;

  // workspace layout IDENTICAL to round-0 (proven ~168 MB)
  float* ws   = (float*)d_ws;
  const size_t NC = (size_t)NTOK * CDIM;
  float* x    = ws;
  float* xn   = x + NC;
  float* qkv  = xn + NC;
  float* att  = qkv + (size_t)NTOK * C3;
  float* hff  = att + NC;
  float* maskT = hff + (size_t)NTOK * FFDIM;
  float* ct   = maskT + (size_t)NEXP * NTOK;
  float* st   = ct + (size_t)TSEQ * 32;
  float* moe_out = att;                        // att dead post-layers
  // MoE-phase aliases into qkv region (3*NC floats, dead post-layers):
  unsigned short* x_bf    = (unsigned short*)qkv;        // bytes [0, 8.4M)
  unsigned short* hmoe_bf = (unsigned short*)qkv + NC;   // bytes [8.4M, 16.8M)
  float* hmoe_f32 = qkv + NC;                            // bytes [16.8M, 33.6M)
  float* tmp2     = qkv + 2 * NC;                        // bytes [33.6M, 50.3M)
  unsigned short* wt_s    = (unsigned short*)hff;        // expert weights, 2.1 MB
  // head-phase aliases:
  unsigned short* xn_bf   = (unsigned short*)qkv;        // x_bf dead by then
  unsigned short* wt_head = (unsigned short*)hff;        // 65.5 MB < 67.1 MB

  embed_kernel<<<NTOK, 256, 0, stream>>>(idx, tok_emb, x);
  rope_table_kernel<<<TSEQ, 32, 0, stream>>>(ct, st);

  for (int l = 0; l < LAYERS; l++) {
    ln_kernel<<<NTOK, 256, 0, stream>>>(x, xn, ln1_g + l * CDIM, ln1_b + l * CDIM);
    gemm_f32<<<dim3(C3 / 64, NTOK / 64), 256, 0, stream>>>(
        xn, qkv_w + (size_t)l * CDIM * C3, qkv, nullptr, nullptr, NTOK, C3, CDIM, 0, 0);
    rope_apply_kernel<<<(NTOK * HEADS * 32) / 256, 256, 0, stream>>>(qkv, ct, st);
    attn_kernel<<<dim3(TSEQ, HEADS, 8), 64, 0, stream>>>(qkv, att);
    gemm_f32<<<dim3(CDIM / 64, NTOK / 64), 256, 0, stream>>>(
        att, proj_w + (size_t)l * CDIM * CDIM, x, nullptr, nullptr, NTOK, CDIM, CDIM, 1, 0);
    ln_kernel<<<NTOK, 256, 0, stream>>>(x, xn, ln2_g + l * CDIM, ln2_b + l * CDIM);
    gemm_f32<<<dim3(FFDIM / 64, NTOK / 64), 256, 0, stream>>>(
        xn, ff_w1 + (size_t)l * CDIM * FFDIM, hff, ff_b1 + (size_t)l * FFDIM, nullptr,
        NTOK, FFDIM, CDIM, 0, 1);
    gemm_f32<<<dim3(CDIM / 64, NTOK / 64), 256, 0, stream>>>(
        hff, ff_w2 + (size_t)l * FFDIM * CDIM, x, ff_b2 + (size_t)l * CDIM, nullptr,
        NTOK, CDIM, FFDIM, 1, 0);
  }

  // --- router reads bit-identical-to-R0 x ---
  router_kernel<<<NTOK, 64, 0, stream>>>(x, router_w, maskT);

  // --- MoE experts: bf16 MFMA (downstream of routing) ---
  cvt_bf16_kernel<<<(NC / 4) / 256, 256, 0, stream>>>(x, x_bf);
  hipMemsetAsync(moe_out, 0, NC * sizeof(float), stream);
  for (int e = 0; e < NEXP; e++) {
    wconv_t_kernel<<<dim3(DEXP / 32, CDIM / 32), 256, 0, stream>>>(
        exp_w1 + (size_t)e * CDIM * DEXP, wt_s, CDIM, DEXP);
    gemm_bf16<<<dim3(DEXP / 128, NTOK / 128), 256, 0, stream>>>(
        x_bf, wt_s, hmoe_f32, NTOK, DEXP, CDIM);
    biasgelu_cvt_kernel<<<((int)(NC / 4)) / 256, 256, 0, stream>>>(
        hmoe_f32, exp_b1 + (size_t)e * DEXP, hmoe_bf, DEXP / 4);
    wconv_t_kernel<<<dim3(CDIM / 32, DEXP / 32), 256, 0, stream>>>(
        exp_w2 + (size_t)e * DEXP * CDIM, wt_s, DEXP, CDIM);
    gemm_bf16<<<dim3(CDIM / 128, NTOK / 128), 256, 0, stream>>>(
        hmoe_bf, wt_s, tmp2, NTOK, CDIM, DEXP);
    scaleadd_kernel<<<((int)(NC / 4)) / 256, 256, 0, stream>>>(
        moe_out, tmp2, exp_b2 + (size_t)e * CDIM, maskT + (size_t)e * NTOK);
  }

  // --- head: bf16 (R4 proven) ---
  ln_bf16_kernel<<<NTOK, 256, 0, stream>>>(moe_out, xn_bf, lnf_g, lnf_b);
  wconv_t_kernel<<<dim3(VOCAB / 32, CDIM / 32), 256, 0, stream>>>(head_w, wt_head, CDIM, VOCAB);
  gemm_bf16<<<dim3(VOCAB / 128, NTOK / 128), 256, 0, stream>>>(
      xn_bf, wt_head, out, NTOK, VOCAB, CDIM);
}

// Round 8
// 4724.611 us; speedup vs baseline: 2.5226x; 1.5741x over previous
//
#include <hip/hip_runtime.h>
#include <math.h>

// MoE-GPT forward, round 8: trunk GEMMs -> split-bf16 MFMA (hi/lo, 3-product
// f32 emulation, rel err ~2^-16 to preserve top-2 routing). Attention f32
// (R0), router f32 (R0), MoE experts + head bf16 (R7-proven).

#define NTOK  4096
#define CDIM  1024
#define HEADS 16
#define DHEAD 64
#define LAYERS 3
#define NEXP  8
#define DEXP  1024
#define TSEQ  512
#define FFDIM 4096
#define VOCAB 32000
#define C3    3072

typedef __attribute__((ext_vector_type(8))) short short8;
typedef __attribute__((ext_vector_type(4))) float f32x4;

__device__ __forceinline__ unsigned short f2bf(float f) {
  unsigned int u = __builtin_bit_cast(unsigned int, f);
  return (unsigned short)((u + 0x7fffu + ((u >> 16) & 1u)) >> 16);  // RNE
}
__device__ __forceinline__ float bf2f(unsigned short h) {
  return __builtin_bit_cast(float, ((unsigned int)h) << 16);
}

// ---------------- embedding gather ----------------
__global__ __launch_bounds__(256) void embed_kernel(const int* __restrict__ idx,
                                                    const float* __restrict__ emb,
                                                    float* __restrict__ x) {
  int i = blockIdx.x * 256 + threadIdx.x;
  int n = i >> 8, c4 = i & 255;
  const float4* src = (const float4*)(emb + (size_t)idx[n] * CDIM);
  ((float4*)(x + (size_t)n * CDIM))[c4] = src[c4];
}

// ---------------- RoPE cos/sin table [T][32] ----------------
__global__ void rope_table_kernel(float* __restrict__ ct, float* __restrict__ st) {
  int t = blockIdx.x, p = threadIdx.x;
  float inv = powf(10000.0f, -(float)p / 32.0f);
  float ang = (float)t * inv;
  ct[t * 32 + p] = cosf(ang);
  st[t * 32 + p] = sinf(ang);
}

// ---------------- RoPE in-place on q,k ----------------
__global__ __launch_bounds__(256) void rope_apply_kernel(float* __restrict__ qkv,
                                                         const float* __restrict__ ct,
                                                         const float* __restrict__ st) {
  int i = blockIdx.x * 256 + threadIdx.x;
  int n = i >> 9;
  int h = (i >> 5) & (HEADS - 1);
  int p = i & 31;
  int t = n & (TSEQ - 1);
  float c0 = ct[t * 32 + p], s0 = st[t * 32 + p];
  size_t base = (size_t)n * C3 + h * DHEAD;
#pragma unroll
  for (int s = 0; s < 2; s++) {
    float* ptr = qkv + base + s * CDIM;
    float a = ptr[p], b = ptr[p + 32];
    ptr[p]      = a * c0 - b * s0;
    ptr[p + 32] = b * c0 + a * s0;
  }
}

// ---------------- LayerNorm f32 -> split hi/lo bf16 ----------------
__global__ __launch_bounds__(256) void ln_split_kernel(const float* __restrict__ x,
                                                       unsigned short* __restrict__ yh,
                                                       unsigned short* __restrict__ yl,
                                                       const float* __restrict__ g,
                                                       const float* __restrict__ b) {
  int n = blockIdx.x, tid = threadIdx.x;
  const float4* xr = (const float4*)(x + (size_t)n * CDIM);
  float4 v = xr[tid];
  float s = v.x + v.y + v.z + v.w;
  float ss = v.x * v.x + v.y * v.y + v.z * v.z + v.w * v.w;
  __shared__ float rs[256], rss[256];
  rs[tid] = s; rss[tid] = ss;
  __syncthreads();
  for (int o = 128; o > 0; o >>= 1) {
    if (tid < o) { rs[tid] += rs[tid + o]; rss[tid] += rss[tid + o]; }
    __syncthreads();
  }
  float m = rs[0] * (1.0f / CDIM);
  float var = rss[0] * (1.0f / CDIM) - m * m;
  float r = rsqrtf(var + 1e-5f);
  float4 gv = ((const float4*)g)[tid];
  float4 bv = ((const float4*)b)[tid];
  float o0 = (v.x - m) * r * gv.x + bv.x;
  float o1 = (v.y - m) * r * gv.y + bv.y;
  float o2 = (v.z - m) * r * gv.z + bv.z;
  float o3 = (v.w - m) * r * gv.w + bv.w;
  ushort4 h, l;
  h.x = f2bf(o0); l.x = f2bf(o0 - bf2f(h.x));
  h.y = f2bf(o1); l.y = f2bf(o1 - bf2f(h.y));
  h.z = f2bf(o2); l.z = f2bf(o2 - bf2f(h.z));
  h.w = f2bf(o3); l.w = f2bf(o3 - bf2f(h.w));
  ((ushort4*)(yh + (size_t)n * CDIM))[tid] = h;
  ((ushort4*)(yl + (size_t)n * CDIM))[tid] = l;
}

// ---------------- f32 -> split hi/lo bf16 ----------------
__global__ __launch_bounds__(256) void cvt_split_kernel(const float* __restrict__ x,
                                                        unsigned short* __restrict__ yh,
                                                        unsigned short* __restrict__ yl) {
  int i = blockIdx.x * 256 + threadIdx.x;
  float4 v = ((const float4*)x)[i];
  ushort4 h, l;
  h.x = f2bf(v.x); l.x = f2bf(v.x - bf2f(h.x));
  h.y = f2bf(v.y); l.y = f2bf(v.y - bf2f(h.y));
  h.z = f2bf(v.z); l.z = f2bf(v.z - bf2f(h.z));
  h.w = f2bf(v.w); l.w = f2bf(v.w - bf2f(h.w));
  ((ushort4*)yh)[i] = h;
  ((ushort4*)yl)[i] = l;
}

// ---------------- f32 -> bf16 convert (R7 proven) ----------------
__global__ __launch_bounds__(256) void cvt_bf16_kernel(const float* __restrict__ x,
                                                       unsigned short* __restrict__ y) {
  int i = blockIdx.x * 256 + threadIdx.x;
  float4 v = ((const float4*)x)[i];
  ushort4 o;
  o.x = f2bf(v.x); o.y = f2bf(v.y); o.z = f2bf(v.z); o.w = f2bf(v.w);
  ((ushort4*)y)[i] = o;
}

// ---------------- LayerNorm f32 -> bf16 (R4 proven) ----------------
__global__ __launch_bounds__(256) void ln_bf16_kernel(const float* __restrict__ x,
                                                      unsigned short* __restrict__ y,
                                                      const float* __restrict__ g,
                                                      const float* __restrict__ b) {
  int n = blockIdx.x, tid = threadIdx.x;
  const float4* xr = (const float4*)(x + (size_t)n * CDIM);
  float4 v = xr[tid];
  float s = v.x + v.y + v.z + v.w;
  float ss = v.x * v.x + v.y * v.y + v.z * v.z + v.w * v.w;
  __shared__ float rs[256], rss[256];
  rs[tid] = s; rss[tid] = ss;
  __syncthreads();
  for (int o = 128; o > 0; o >>= 1) {
    if (tid < o) { rs[tid] += rs[tid + o]; rss[tid] += rss[tid + o]; }
    __syncthreads();
  }
  float m = rs[0] * (1.0f / CDIM);
  float var = rss[0] * (1.0f / CDIM) - m * m;
  float r = rsqrtf(var + 1e-5f);
  float4 gv = ((const float4*)g)[tid];
  float4 bv = ((const float4*)b)[tid];
  ushort4 o4;
  o4.x = f2bf((v.x - m) * r * gv.x + bv.x);
  o4.y = f2bf((v.y - m) * r * gv.y + bv.y);
  o4.z = f2bf((v.z - m) * r * gv.z + bv.z);
  o4.w = f2bf((v.w - m) * r * gv.w + bv.w);
  ((ushort4*)(y + (size_t)n * CDIM))[tid] = o4;
}

// ---------------- elementwise: out_bf16 = gelu(in + bias[col]) (R7 proven) ----------------
__global__ __launch_bounds__(256) void biasgelu_cvt_kernel(const float* __restrict__ in,
                                                           const float* __restrict__ bias,
                                                           unsigned short* __restrict__ out,
                                                           int Fm4) {
  int i = blockIdx.x * 256 + threadIdx.x;
  int c4 = (i & (Fm4 - 1)) << 2;
  float4 v = ((const float4*)in)[i];
  float4 b = *(const float4*)(bias + c4);
  float a0 = v.x + b.x, a1 = v.y + b.y, a2 = v.z + b.z, a3 = v.w + b.w;
  ushort4 o;
  o.x = f2bf(0.5f * a0 * (1.0f + erff(a0 * 0.70710678118654752f)));
  o.y = f2bf(0.5f * a1 * (1.0f + erff(a1 * 0.70710678118654752f)));
  o.z = f2bf(0.5f * a2 * (1.0f + erff(a2 * 0.70710678118654752f)));
  o.w = f2bf(0.5f * a3 * (1.0f + erff(a3 * 0.70710678118654752f)));
  ((ushort4*)out)[i] = o;
}

// ---------------- elementwise: x += t  (proj residual) ----------------
__global__ __launch_bounds__(256) void addres_kernel(float* __restrict__ x,
                                                     const float* __restrict__ t) {
  int i = blockIdx.x * 256 + threadIdx.x;
  float4 xv = ((const float4*)x)[i];
  float4 tv = ((const float4*)t)[i];
  xv.x += tv.x; xv.y += tv.y; xv.z += tv.z; xv.w += tv.w;
  ((float4*)x)[i] = xv;
}

// ---------------- elementwise: x += t + bias[col] (FF2 residual) ----------------
__global__ __launch_bounds__(256) void add2_kernel(float* __restrict__ x,
                                                   const float* __restrict__ t,
                                                   const float* __restrict__ bias) {
  int i = blockIdx.x * 256 + threadIdx.x;
  int c4 = (i & (CDIM / 4 - 1)) << 2;
  float4 xv = ((const float4*)x)[i];
  float4 tv = ((const float4*)t)[i];
  float4 b = *(const float4*)(bias + c4);
  xv.x += tv.x + b.x; xv.y += tv.y + b.y; xv.z += tv.z + b.z; xv.w += tv.w + b.w;
  ((float4*)x)[i] = xv;
}

// ---------------- elementwise: o += rs[row] * (t + bias[col]) (R7 proven) ----------------
__global__ __launch_bounds__(256) void scaleadd_kernel(float* __restrict__ o,
                                                       const float* __restrict__ t,
                                                       const float* __restrict__ bias,
                                                       const float* __restrict__ rs) {
  int i = blockIdx.x * 256 + threadIdx.x;
  int m = i >> 8;
  int c4 = (i & (CDIM / 4 - 1)) << 2;
  float w = rs[m];
  float4 ov = ((const float4*)o)[i];
  float4 tv = ((const float4*)t)[i];
  float4 b = *(const float4*)(bias + c4);
  ov.x += w * (tv.x + b.x); ov.y += w * (tv.y + b.y);
  ov.z += w * (tv.z + b.z); ov.w += w * (tv.w + b.w);
  ((float4*)o)[i] = ov;
}

// ---------------- weight transpose+convert bf16 (R4 proven) ----------------
__global__ __launch_bounds__(256) void wconv_t_kernel(const float* __restrict__ W,
                                                      unsigned short* __restrict__ Wt,
                                                      int K, int N) {
  __shared__ float t[32][33];
  int n0 = blockIdx.x * 32, k0 = blockIdx.y * 32;
  int tx = threadIdx.x & 31, ty = threadIdx.x >> 5;
#pragma unroll
  for (int i = 0; i < 4; i++)
    t[ty + 8 * i][tx] = W[(size_t)(k0 + ty + 8 * i) * N + n0 + tx];
  __syncthreads();
#pragma unroll
  for (int i = 0; i < 4; i++)
    Wt[(size_t)(n0 + ty + 8 * i) * K + k0 + tx] = f2bf(t[tx][ty + 8 * i]);
}

// ---------------- weight transpose + hi/lo split: f32 [K][N] -> bf16 [N][K] x2 ----------------
__global__ __launch_bounds__(256) void wconv_split_kernel(const float* __restrict__ W,
                                                          unsigned short* __restrict__ Wh,
                                                          unsigned short* __restrict__ Wl,
                                                          int K, int N) {
  __shared__ float t[32][33];
  int n0 = blockIdx.x * 32, k0 = blockIdx.y * 32;
  int tx = threadIdx.x & 31, ty = threadIdx.x >> 5;
#pragma unroll
  for (int i = 0; i < 4; i++)
    t[ty + 8 * i][tx] = W[(size_t)(k0 + ty + 8 * i) * N + n0 + tx];
  __syncthreads();
#pragma unroll
  for (int i = 0; i < 4; i++) {
    float w = t[tx][ty + 8 * i];
    unsigned short h = f2bf(w);
    size_t o = (size_t)(n0 + ty + 8 * i) * K + k0 + tx;
    Wh[o] = h;
    Wl[o] = f2bf(w - bf2f(h));
  }
}

// ---------------- split-bf16 MFMA GEMM (f32 emulation, 3 products) ----------------
// C = (Ah+Al)[M][K] @ (Bth+Btl)[N][K]^T   (drops Al*Btl, rel err ~2^-16)
// FUSE 0: C[m][n] = v (f32)   FUSE 1: gelu(v+bias[n]) -> split store Ch,Cl (bf16)
template <int FUSE>
__global__ __launch_bounds__(256) void gemm_split(const unsigned short* __restrict__ Ah,
                                                  const unsigned short* __restrict__ Al,
                                                  const unsigned short* __restrict__ Bth,
                                                  const unsigned short* __restrict__ Btl,
                                                  float* __restrict__ C,
                                                  unsigned short* __restrict__ Ch,
                                                  unsigned short* __restrict__ Cl,
                                                  const float* __restrict__ bias,
                                                  int M, int Nn, int K) {
  __shared__ __align__(16) unsigned short AsH[128 * 32];
  __shared__ __align__(16) unsigned short AsL[128 * 32];
  __shared__ __align__(16) unsigned short BsH[128 * 32];
  __shared__ __align__(16) unsigned short BsL[128 * 32];
  const int tid = threadIdx.x;
  const int wv = tid >> 6, ln = tid & 63;
  const int bm = blockIdx.y * 128, bn = blockIdx.x * 128;

  const size_t aoff0 = (size_t)(bm + 32 * wv + (ln >> 2)) * K + (size_t)((ln & 3) * 8);
  const size_t aoff1 = aoff0 + (size_t)16 * K;
  const size_t boff0 = (size_t)(bn + 32 * wv + (ln >> 2)) * K + (size_t)((ln & 3) * 8);
  const size_t boff1 = boff0 + (size_t)16 * K;
  const int lofs = 1024 * wv + ln * 8;

  const int wm = wv >> 1, wn = wv & 1;
  const int lr = ln & 15, lg = ln >> 4;

  f32x4 acc[4][4];
#pragma unroll
  for (int i = 0; i < 4; i++)
#pragma unroll
    for (int j = 0; j < 4; j++) acc[i][j] = (f32x4){0.f, 0.f, 0.f, 0.f};

  for (int k0 = 0; k0 < K; k0 += 32) {
    short8 rah0 = *(const short8*)(Ah + aoff0 + k0);
    short8 rah1 = *(const short8*)(Ah + aoff1 + k0);
    short8 ral0 = *(const short8*)(Al + aoff0 + k0);
    short8 ral1 = *(const short8*)(Al + aoff1 + k0);
    short8 rbh0 = *(const short8*)(Bth + boff0 + k0);
    short8 rbh1 = *(const short8*)(Bth + boff1 + k0);
    short8 rbl0 = *(const short8*)(Btl + boff0 + k0);
    short8 rbl1 = *(const short8*)(Btl + boff1 + k0);
    __syncthreads();
    *(short8*)(AsH + lofs)       = rah0;
    *(short8*)(AsH + lofs + 512) = rah1;
    *(short8*)(AsL + lofs)       = ral0;
    *(short8*)(AsL + lofs + 512) = ral1;
    *(short8*)(BsH + lofs)       = rbh0;
    *(short8*)(BsH + lofs + 512) = rbh1;
    *(short8*)(BsL + lofs)       = rbl0;
    *(short8*)(BsL + lofs + 512) = rbl1;
    __syncthreads();

    short8 afh[4], afl[4], bwh[4], bwl[4];
#pragma unroll
    for (int i = 0; i < 4; i++) {
      const int ao = (64 * wm + 16 * i + lr) * 32 + 8 * lg;
      afh[i] = *(const short8*)(AsH + ao);
      afl[i] = *(const short8*)(AsL + ao);
    }
#pragma unroll
    for (int j = 0; j < 4; j++) {
      const int bo = (64 * wn + 16 * j + lr) * 32 + 8 * lg;
      bwh[j] = *(const short8*)(BsH + bo);
      bwl[j] = *(const short8*)(BsL + bo);
    }
#pragma unroll
    for (int i = 0; i < 4; i++)
#pragma unroll
      for (int j = 0; j < 4; j++) {
        acc[i][j] = __builtin_amdgcn_mfma_f32_16x16x32_bf16(afh[i], bwh[j], acc[i][j], 0, 0, 0);
        acc[i][j] = __builtin_amdgcn_mfma_f32_16x16x32_bf16(afl[i], bwh[j], acc[i][j], 0, 0, 0);
        acc[i][j] = __builtin_amdgcn_mfma_f32_16x16x32_bf16(afh[i], bwl[j], acc[i][j], 0, 0, 0);
      }
  }

#pragma unroll
  for (int j = 0; j < 4; j++) {
    const int n = bn + 64 * wn + 16 * j + lr;
#pragma unroll
    for (int i = 0; i < 4; i++) {
#pragma unroll
      for (int rr = 0; rr < 4; rr++) {
        const int m = bm + 64 * wm + 16 * i + 4 * lg + rr;
        float v = acc[i][j][rr];
        const size_t ci = (size_t)m * Nn + n;
        if constexpr (FUSE == 1) {
          v += bias[n];
          v = 0.5f * v * (1.0f + erff(v * 0.70710678118654752f));
          unsigned short h = f2bf(v);
          Ch[ci] = h;
          Cl[ci] = f2bf(v - bf2f(h));
        } else {
          C[ci] = v;
        }
      }
    }
  }
}

// ---------------- bf16 MFMA GEMM (R4/R7 proven; MoE + head) ----------------
__global__ __launch_bounds__(256) void gemm_bf16(const unsigned short* __restrict__ A,
                                                 const unsigned short* __restrict__ Bt,
                                                 float* __restrict__ C,
                                                 int M, int Nn, int K) {
  __shared__ __align__(16) unsigned short As[128 * 32];
  __shared__ __align__(16) unsigned short Bs[128 * 32];
  const int tid = threadIdx.x;
  const int wv = tid >> 6, ln = tid & 63;
  const int bm = blockIdx.y * 128, bn = blockIdx.x * 128;

  const size_t aoff0 = (size_t)(bm + 32 * wv + (ln >> 2)) * K + (size_t)((ln & 3) * 8);
  const size_t aoff1 = aoff0 + (size_t)16 * K;
  const size_t boff0 = (size_t)(bn + 32 * wv + (ln >> 2)) * K + (size_t)((ln & 3) * 8);
  const size_t boff1 = boff0 + (size_t)16 * K;
  const int lofs = 1024 * wv + ln * 8;

  const int wm = wv >> 1, wn = wv & 1;
  const int lr = ln & 15, lg = ln >> 4;

  f32x4 acc[4][4];
#pragma unroll
  for (int i = 0; i < 4; i++)
#pragma unroll
    for (int j = 0; j < 4; j++) acc[i][j] = (f32x4){0.f, 0.f, 0.f, 0.f};

  for (int k0 = 0; k0 < K; k0 += 32) {
    short8 ra0 = *(const short8*)(A + aoff0 + k0);
    short8 ra1 = *(const short8*)(A + aoff1 + k0);
    short8 rb0 = *(const short8*)(Bt + boff0 + k0);
    short8 rb1 = *(const short8*)(Bt + boff1 + k0);
    __syncthreads();
    *(short8*)(As + lofs)       = ra0;
    *(short8*)(As + lofs + 512) = ra1;
    *(short8*)(Bs + lofs)       = rb0;
    *(short8*)(Bs + lofs + 512) = rb1;
    __syncthreads();

    short8 af[4], bw[4];
#pragma unroll
    for (int i = 0; i < 4; i++)
      af[i] = *(const short8*)(As + ((64 * wm + 16 * i + lr) * 32 + 8 * lg));
#pragma unroll
    for (int j = 0; j < 4; j++)
      bw[j] = *(const short8*)(Bs + ((64 * wn + 16 * j + lr) * 32 + 8 * lg));
#pragma unroll
    for (int i = 0; i < 4; i++)
#pragma unroll
      for (int j = 0; j < 4; j++)
        acc[i][j] = __builtin_amdgcn_mfma_f32_16x16x32_bf16(af[i], bw[j], acc[i][j], 0, 0, 0);
  }

#pragma unroll
  for (int j = 0; j < 4; j++) {
    const int n = bn + 64 * wn + 16 * j + lr;
#pragma unroll
    for (int i = 0; i < 4; i++) {
#pragma unroll
      for (int r = 0; r < 4; r++) {
        const int m = bm + 64 * wm + 16 * i + 4 * lg + r;
        C[(size_t)m * Nn + n] = acc[i][j][r];
      }
    }
  }
}

// ---------------- causal attention f32 (R0 proven) ----------------
__global__ __launch_bounds__(64) void attn_kernel(const float* __restrict__ qkv,
                                                  float* __restrict__ att) {
  int q = blockIdx.x, h = blockIdx.y, b = blockIdx.z;
  int lane = threadIdx.x;
  __shared__ float qv[64];
  __shared__ float sc[512];
  const float* qrow = qkv + ((size_t)(b * TSEQ + q)) * C3 + h * DHEAD;
  qv[lane] = qrow[lane];
  __syncthreads();
  int nk = q + 1;
  float lmax = -1e30f;
  for (int k = lane; k < nk; k += 64) {
    const float* krow = qkv + ((size_t)(b * TSEQ + k)) * C3 + CDIM + h * DHEAD;
    float s = 0.0f;
#pragma unroll
    for (int dd = 0; dd < 64; dd++) s += qv[dd] * krow[dd];
    s *= 0.125f;
    sc[k] = s;
    lmax = fmaxf(lmax, s);
  }
  for (int m = 32; m >= 1; m >>= 1) lmax = fmaxf(lmax, __shfl_xor(lmax, m));
  __syncthreads();
  float lsum = 0.0f;
  for (int k = lane; k < nk; k += 64) {
    float p = expf(sc[k] - lmax);
    sc[k] = p;
    lsum += p;
  }
  for (int m = 32; m >= 1; m >>= 1) lsum += __shfl_xor(lsum, m);
  float inv = 1.0f / lsum;
  __syncthreads();
  float accv = 0.0f;
  for (int k = 0; k < nk; k++) {
    const float* vrow = qkv + ((size_t)(b * TSEQ + k)) * C3 + 2 * CDIM + h * DHEAD;
    accv += sc[k] * vrow[lane];
  }
  att[((size_t)(b * TSEQ + q)) * CDIM + h * DHEAD + lane] = accv * inv;
}

// ---------------- router (R0 proven) ----------------
__global__ __launch_bounds__(64) void router_kernel(const float* __restrict__ x,
                                                    const float* __restrict__ rw,
                                                    float* __restrict__ maskT) {
  int n = blockIdx.x, lane = threadIdx.x;
  const float* xr = x + (size_t)n * CDIM;
  float acc[NEXP] = {};
  for (int i = 0; i < CDIM / 64; i++) {
    int c = lane + 64 * i;
    float xv = xr[c];
    const float* r = rw + (size_t)c * NEXP;
#pragma unroll
    for (int e = 0; e < NEXP; e++) acc[e] += xv * r[e];
  }
  for (int m = 32; m >= 1; m >>= 1)
#pragma unroll
    for (int e = 0; e < NEXP; e++) acc[e] += __shfl_xor(acc[e], m);
  if (lane == 0) {
    float mx = acc[0];
#pragma unroll
    for (int e = 1; e < NEXP; e++) mx = fmaxf(mx, acc[e]);
    float p[NEXP];
#pragma unroll
    for (int e = 0; e < NEXP; e++) p[e] = expf(acc[e] - mx);
    int i1 = 0;
#pragma unroll
    for (int e = 1; e < NEXP; e++) if (p[e] > p[i1]) i1 = e;
    int i2 = (i1 == 0) ? 1 : 0;
#pragma unroll
    for (int e = 0; e < NEXP; e++) if (e != i1 && p[e] > p[i2]) i2 = e;
    float denom = p[i1] + p[i2];
    float w1 = p[i1] / denom, w2 = p[i2] / denom;
#pragma unroll
    for (int e = 0; e < NEXP; e++) maskT[(size_t)e * NTOK + n] = 0.0f;
    maskT[(size_t)i1 * NTOK + n] = w1;
    maskT[(size_t)i2 * NTOK + n] = w2;
  }
}

extern "C" void kernel_launch(void* const* d_in, const int* in_sizes, int n_in,
                              void* d_out, int out_size, void* d_ws, size_t ws_size,
                              hipStream_t stream) {
  const int*   idx      = (const int*)d_in[0];
  const float* tok_emb  = (const float*)d_in[1];
  const float* ln1_g    = (const float*)d_in[2];
  const float* ln1_b    = (const float*)d_in[3];
  const float* ln2_g    = (const float*)d_in[4];
  const float* ln2_b    = (const float*)d_in[5];
  const float* qkv_w    = (const float*)d_in[6];
  const float* proj_w   = (const float*)d_in[7];
  const float* ff_w1    = (const float*)d_in[8];
  const float* ff_b1    = (const float*)d_in[9];
  const float* ff_w2    = (const float*)d_in[10];
  const float* ff_b2    = (const float*)d_in[11];
  const float* router_w = (const float*)d_in[12];
  const float* exp_w1   = (const float*)d_in[13];
  const float* exp_b1   = (const float*)d_in[14];
  const float* exp_w2   = (const float*)d_in[15];
  const float* exp_b2   = (const float*)d_in[16];
  const float* lnf_g    = (const float*)d_in[17];
  const float* lnf_b    = (const float*)d_in[18];
  const float* head_w   = (const float*)d_in[19];
  float* out = (float*)d_out;

  // ---- workspace layout (~117.9 MB) ----
  const size_t NC = (size_t)NTOK * CDIM;                      // 4M elements
  char* w = (char*)d_ws;
  float* x  = (float*)w;                 w += NC * 4;         // 16.78 MB
  unsigned short* S1 = (unsigned short*)w; w += NC * 4;       // 16.78 MB (2x NC shorts)
  float* Q  = (float*)w;                 w += (size_t)NTOK * C3 * 4;  // 50.33 MB
  float* C3r = (float*)w;                w += NC * 4;         // 16.78 MB (adjacent to Q)
  unsigned short* WS = (unsigned short*)w; w += (size_t)CDIM * FFDIM * 2 * 2; // 16.78 MB
  float* maskT = (float*)w;              w += (size_t)NEXP * NTOK * 4;
  float* ct = (float*)w;                 w += (size_t)TSEQ * 32 * 4;
  float* st = (float*)w;                 w += (size_t)TSEQ * 32 * 4;

  // trunk aliases
  unsigned short* xh = S1;                                    // [N][C] bf16
  unsigned short* xl = S1 + NC;
  unsigned short* Wh = WS;                                    // [N][K] bf16, <= 8.39MB
  unsigned short* Wl = WS + (size_t)CDIM * FFDIM;
  float* qkvf = Q;                                            // [N][3C] f32
  float* attf = C3r;                                          // [N][C] f32 (attn out / proj tmp)
  unsigned short* hh = (unsigned short*)Q;                    // FF hidden hi [N][FF] (33.55MB)
  unsigned short* hl = (unsigned short*)Q + (size_t)NTOK * FFDIM;  // lo, spills into C3r
  float* tmpS1 = (float*)S1;                                  // FF2 out f32 (xh/xl dead)
  // MoE aliases
  unsigned short* x_bf    = S1;
  unsigned short* hmoe_bf = S1 + NC;
  float* hmoe_f32 = C3r;
  float* tmp2     = Q;                                        // first NC floats of Q
  float* moe_out  = x;                                        // x dead after cvt
  unsigned short* wt_s = WS;
  // head aliases
  unsigned short* xn_bf   = S1;
  unsigned short* wt_head = (unsigned short*)Q;               // 65.5MB across Q+C3r

  embed_kernel<<<NTOK, 256, 0, stream>>>(idx, tok_emb, x);
  rope_table_kernel<<<TSEQ, 32, 0, stream>>>(ct, st);

  for (int l = 0; l < LAYERS; l++) {
    // --- attention sublayer (split GEMMs, f32 attention core) ---
    ln_split_kernel<<<NTOK, 256, 0, stream>>>(x, xh, xl, ln1_g + l * CDIM, ln1_b + l * CDIM);
    wconv_split_kernel<<<dim3(C3 / 32, CDIM / 32), 256, 0, stream>>>(
        qkv_w + (size_t)l * CDIM * C3, Wh, Wl, CDIM, C3);
    gemm_split<0><<<dim3(C3 / 128, NTOK / 128), 256, 0, stream>>>(
        xh, xl, Wh, Wl, qkvf, nullptr, nullptr, nullptr, NTOK, C3, CDIM);
    rope_apply_kernel<<<(NTOK * HEADS * 32) / 256, 256, 0, stream>>>(qkvf, ct, st);
    attn_kernel<<<dim3(TSEQ, HEADS, 8), 64, 0, stream>>>(qkvf, attf);
    cvt_split_kernel<<<(NC / 4) / 256, 256, 0, stream>>>(attf, xh, xl);
    wconv_split_kernel<<<dim3(CDIM / 32, CDIM / 32), 256, 0, stream>>>(
        proj_w + (size_t)l * CDIM * CDIM, Wh, Wl, CDIM, CDIM);
    gemm_split<0><<<dim3(CDIM / 128, NTOK / 128), 256, 0, stream>>>(
        xh, xl, Wh, Wl, attf, nullptr, nullptr, nullptr, NTOK, CDIM, CDIM);
    addres_kernel<<<(NC / 4) / 256, 256, 0, stream>>>(x, attf);
    // --- FF sublayer (split GEMMs, fused gelu+split epilogue) ---
    ln_split_kernel<<<NTOK, 256, 0, stream>>>(x, xh, xl, ln2_g + l * CDIM, ln2_b + l * CDIM);
    wconv_split_kernel<<<dim3(FFDIM / 32, CDIM / 32), 256, 0, stream>>>(
        ff_w1 + (size_t)l * CDIM * FFDIM, Wh, Wl, CDIM, FFDIM);
    gemm_split<1><<<dim3(FFDIM / 128, NTOK / 128), 256, 0, stream>>>(
        xh, xl, Wh, Wl, nullptr, hh, hl, ff_b1 + (size_t)l * FFDIM, NTOK, FFDIM, CDIM);
    wconv_split_kernel<<<dim3(CDIM / 32, FFDIM / 32), 256, 0, stream>>>(
        ff_w2 + (size_t)l * FFDIM * CDIM, Wh, Wl, FFDIM, CDIM);
    gemm_split<0><<<dim3(CDIM / 128, NTOK / 128), 256, 0, stream>>>(
        hh, hl, Wh, Wl, tmpS1, nullptr, nullptr, nullptr, NTOK, CDIM, FFDIM);
    add2_kernel<<<(NC / 4) / 256, 256, 0, stream>>>(x, tmpS1, ff_b2 + (size_t)l * CDIM);
  }

  // --- router on exact-trunk x, then MoE bf16 (R7 proven) ---
  router_kernel<<<NTOK, 64, 0, stream>>>(x, router_w, maskT);
  cvt_bf16_kernel<<<(NC / 4) / 256, 256, 0, stream>>>(x, x_bf);
  hipMemsetAsync(moe_out, 0, NC * sizeof(float), stream);
  for (int e = 0; e < NEXP; e++) {
    wconv_t_kernel<<<dim3(DEXP / 32, CDIM / 32), 256, 0, stream>>>(
        exp_w1 + (size_t)e * CDIM * DEXP, wt_s, CDIM, DEXP);
    gemm_bf16<<<dim3(DEXP / 128, NTOK / 128), 256, 0, stream>>>(
        x_bf, wt_s, hmoe_f32, NTOK, DEXP, CDIM);
    biasgelu_cvt_kernel<<<((int)(NC / 4)) / 256, 256, 0, stream>>>(
        hmoe_f32, exp_b1 + (size_t)e * DEXP, hmoe_bf, DEXP / 4);
    wconv_t_kernel<<<dim3(CDIM / 32, DEXP / 32), 256, 0, stream>>>(
        exp_w2 + (size_t)e * DEXP * CDIM, wt_s, DEXP, CDIM);
    gemm_bf16<<<dim3(CDIM / 128, NTOK / 128), 256, 0, stream>>>(
        hmoe_bf, wt_s, tmp2, NTOK, CDIM, DEXP);
    scaleadd_kernel<<<((int)(NC / 4)) / 256, 256, 0, stream>>>(
        moe_out, tmp2, exp_b2 + (size_t)e * CDIM, maskT + (size_t)e * NTOK);
  }

  // --- head: bf16 (R4/R7 proven) ---
  ln_bf16_kernel<<<NTOK, 256, 0, stream>>>(moe_out, xn_bf, lnf_g, lnf_b);
  wconv_t_kernel<<<dim3(VOCAB / 32, CDIM / 32), 256, 0, stream>>>(head_w, wt_head, CDIM, VOCAB);
  gemm_bf16<<<dim3(VOCAB / 128, NTOK / 128), 256, 0, stream>>>(
      xn_bf, wt_head, out, NTOK, VOCAB, CDIM);
}

// Round 13
// 2960.402 us; speedup vs baseline: 4.0259x; 1.5959x over previous
//
#include <hip/hip_runtime.h>
#include <math.h>

// MoE-GPT forward, round 13: flash attention with 3-WAY bf16 split (hi/mid/lo,
// rep. error 2^-24; 6 cross-products => total ~2^-23, 128x below the 2^-16
// band that flipped routing in R10-R12). Flash structure = R11 (validated by
// R10===R12 equivalence). Trunk split-GEMMs (R8), MoE/head bf16 (R7).

#define NTOK  4096
#define CDIM  1024
#define HEADS 16
#define DHEAD 64
#define LAYERS 3
#define NEXP  8
#define DEXP  1024
#define TSEQ  512
#define FFDIM 4096
#define VOCAB 32000
#define C3    3072

typedef __attribute__((ext_vector_type(8))) short short8;
typedef __attribute__((ext_vector_type(4))) float f32x4;

__device__ __forceinline__ unsigned short f2bf(float f) {
  unsigned int u = __builtin_bit_cast(unsigned int, f);
  return (unsigned short)((u + 0x7fffu + ((u >> 16) & 1u)) >> 16);  // RNE
}
__device__ __forceinline__ float bf2f(unsigned short h) {
  return __builtin_bit_cast(float, ((unsigned int)h) << 16);
}

// ---------------- embedding gather ----------------
__global__ __launch_bounds__(256) void embed_kernel(const int* __restrict__ idx,
                                                    const float* __restrict__ emb,
                                                    float* __restrict__ x) {
  int i = blockIdx.x * 256 + threadIdx.x;
  int n = i >> 8, c4 = i & 255;
  const float4* src = (const float4*)(emb + (size_t)idx[n] * CDIM);
  ((float4*)(x + (size_t)n * CDIM))[c4] = src[c4];
}

// ---------------- RoPE cos/sin table [T][32] ----------------
__global__ void rope_table_kernel(float* __restrict__ ct, float* __restrict__ st) {
  int t = blockIdx.x, p = threadIdx.x;
  float inv = powf(10000.0f, -(float)p / 32.0f);
  float ang = (float)t * inv;
  ct[t * 32 + p] = cosf(ang);
  st[t * 32 + p] = sinf(ang);
}

// ---------------- qkv prep: RoPE + 3-way split + head-major relayout ----------------
// in: qkv f32 [N][3C]. out: Q{h,m,l}, K{h,m,l} [bh][T][64]; Vt{h,m,l} [bh][64][T].
__global__ __launch_bounds__(256) void qkv_prep_kernel(
    const float* __restrict__ qkv, const float* __restrict__ ct,
    const float* __restrict__ st,
    unsigned short* __restrict__ Qh, unsigned short* __restrict__ Qm,
    unsigned short* __restrict__ Ql,
    unsigned short* __restrict__ Kh, unsigned short* __restrict__ Km,
    unsigned short* __restrict__ Kl,
    unsigned short* __restrict__ Vth, unsigned short* __restrict__ Vtm,
    unsigned short* __restrict__ Vtl) {
  __shared__ unsigned short sVh[64 * 64], sVm[64 * 64], sVl[64 * 64];  // [d][t]
  const int tid = threadIdx.x;
  const int tt0 = blockIdx.x * 64, h = blockIdx.y, b = blockIdx.z;
  const int bh = b * HEADS + h;
#pragma unroll
  for (int u = 0; u < 8; u++) {
    int pidx = tid + u * 256;                 // 2048 pairs = 64 t x 32 p
    int tl = pidx >> 5, p = pidx & 31;
    int t = tt0 + tl;
    size_t nb = ((size_t)(b * TSEQ + t)) * C3 + h * DHEAD;
    float c0 = ct[t * 32 + p], s0 = st[t * 32 + p];
    size_t ob = ((size_t)bh * TSEQ + t) * 64;
    // q
    float a = qkv[nb + p], bb = qkv[nb + p + 32];
    float lo = a * c0 - bb * s0, hi = bb * c0 + a * s0;
    unsigned short w0, w1;
    float r;
    w0 = f2bf(lo); r = lo - bf2f(w0); w1 = f2bf(r); r -= bf2f(w1);
    Qh[ob + p] = w0; Qm[ob + p] = w1; Ql[ob + p] = f2bf(r);
    w0 = f2bf(hi); r = hi - bf2f(w0); w1 = f2bf(r); r -= bf2f(w1);
    Qh[ob + p + 32] = w0; Qm[ob + p + 32] = w1; Ql[ob + p + 32] = f2bf(r);
    // k
    a = qkv[nb + CDIM + p]; bb = qkv[nb + CDIM + p + 32];
    lo = a * c0 - bb * s0; hi = bb * c0 + a * s0;
    w0 = f2bf(lo); r = lo - bf2f(w0); w1 = f2bf(r); r -= bf2f(w1);
    Kh[ob + p] = w0; Km[ob + p] = w1; Kl[ob + p] = f2bf(r);
    w0 = f2bf(hi); r = hi - bf2f(w0); w1 = f2bf(r); r -= bf2f(w1);
    Kh[ob + p + 32] = w0; Km[ob + p + 32] = w1; Kl[ob + p + 32] = f2bf(r);
  }
  // V: read [t][d] f32, 3-way split into LDS [d][t], write coalesced
#pragma unroll
  for (int u = 0; u < 4; u++) {
    int vidx = tid + u * 256;                 // 1024 float4s = 64 t x 16
    int tl = vidx >> 4, d4 = (vidx & 15) * 4;
    int t = tt0 + tl;
    float4 v = *(const float4*)(qkv + ((size_t)(b * TSEQ + t)) * C3 + 2 * CDIM + h * DHEAD + d4);
    float vv[4] = {v.x, v.y, v.z, v.w};
#pragma unroll
    for (int j = 0; j < 4; j++) {
      unsigned short w0 = f2bf(vv[j]);
      float r = vv[j] - bf2f(w0);
      unsigned short w1 = f2bf(r);
      r -= bf2f(w1);
      sVh[(d4 + j) * 64 + tl] = w0;
      sVm[(d4 + j) * 64 + tl] = w1;
      sVl[(d4 + j) * 64 + tl] = f2bf(r);
    }
  }
  __syncthreads();
#pragma unroll
  for (int u = 0; u < 2; u++) {
    int idx = tid + u * 256;                  // 512 short8 = 64 d x 8 seg
    int d = idx >> 3, seg = (idx & 7) * 8;
    size_t go = ((size_t)bh * 64 + d) * TSEQ + tt0 + seg;
    *(short8*)(Vth + go) = *(const short8*)(sVh + d * 64 + seg);
    *(short8*)(Vtm + go) = *(const short8*)(sVm + d * 64 + seg);
    *(short8*)(Vtl + go) = *(const short8*)(sVl + d * 64 + seg);
  }
}

// ---------------- flash attention, 3-way-split bf16 MFMA (6 products) ----------------
// grid (T/64, H, B), 256 thr. Wave w owns q rows [qt*64+16w, +16).
__global__ __launch_bounds__(256) void flash_attn_kernel(
    const unsigned short* __restrict__ Qh, const unsigned short* __restrict__ Qm,
    const unsigned short* __restrict__ Ql,
    const unsigned short* __restrict__ Kh, const unsigned short* __restrict__ Km,
    const unsigned short* __restrict__ Kl,
    const unsigned short* __restrict__ Vth, const unsigned short* __restrict__ Vtm,
    const unsigned short* __restrict__ Vtl,
    float* __restrict__ att) {
  __shared__ __align__(16) unsigned short sK[3][2][64 * 32];
  __shared__ __align__(16) unsigned short sV[3][2][64 * 32];
  __shared__ __align__(16) unsigned short sP[3][2][4][16 * 32];
  const int tid = threadIdx.x;
  const int wv = tid >> 6, ln = tid & 63;
  const int qt = blockIdx.x, h = blockIdx.y, b = blockIdx.z;
  const int bh = b * HEADS + h;
  const int lr = ln & 15, lg = ln >> 4;
  const int q0 = qt * 64 + wv * 16;

  // Q fragments: 3 levels x 2 d-chunks
  const size_t qoff = ((size_t)bh * TSEQ + q0 + lr) * 64 + 8 * lg;
  short8 qf[3][2];
  qf[0][0] = *(const short8*)(Qh + qoff); qf[0][1] = *(const short8*)(Qh + qoff + 32);
  qf[1][0] = *(const short8*)(Qm + qoff); qf[1][1] = *(const short8*)(Qm + qoff + 32);
  qf[2][0] = *(const short8*)(Ql + qoff); qf[2][1] = *(const short8*)(Ql + qoff + 32);

  f32x4 Y[4];
#pragma unroll
  for (int j = 0; j < 4; j++) Y[j] = (f32x4){0.f, 0.f, 0.f, 0.f};
  float m[4] = {-1e30f, -1e30f, -1e30f, -1e30f};
  float l[4] = {0.f, 0.f, 0.f, 0.f};

  const int r0 = tid >> 3, sg = (tid & 7) * 8;   // staging: row, seg (shorts)
  const int half = sg >> 5, soff = (sg & 31);

  for (int kt = 0; kt <= qt; kt++) {
    const int kb = kt * 64;
    short8 stg[12];
#pragma unroll
    for (int u = 0; u < 2; u++) {
      int row = r0 + 32 * u;
      size_t gk = ((size_t)bh * TSEQ + kb + row) * 64 + sg;
      size_t gv = ((size_t)bh * 64 + row) * TSEQ + kb + sg;
      stg[u * 6 + 0] = *(const short8*)(Kh + gk);
      stg[u * 6 + 1] = *(const short8*)(Km + gk);
      stg[u * 6 + 2] = *(const short8*)(Kl + gk);
      stg[u * 6 + 3] = *(const short8*)(Vth + gv);
      stg[u * 6 + 4] = *(const short8*)(Vtm + gv);
      stg[u * 6 + 5] = *(const short8*)(Vtl + gv);
    }
    __syncthreads();                  // all waves done reading LDS (prev iter)
#pragma unroll
    for (int u = 0; u < 2; u++) {
      int off = (r0 + 32 * u) * 32 + soff;
      *(short8*)(&sK[0][half][off]) = stg[u * 6 + 0];
      *(short8*)(&sK[1][half][off]) = stg[u * 6 + 1];
      *(short8*)(&sK[2][half][off]) = stg[u * 6 + 2];
      *(short8*)(&sV[0][half][off]) = stg[u * 6 + 3];
      *(short8*)(&sV[1][half][off]) = stg[u * 6 + 4];
      *(short8*)(&sV[2][half][off]) = stg[u * 6 + 5];
    }
    __syncthreads();                  // K/V tile visible

    // S = QK^T with 3-way split, 6 significant products x 2 chunks = 12 MFMA/tile
    f32x4 s[4];
#pragma unroll
    for (int j = 0; j < 4; j++) s[j] = (f32x4){0.f, 0.f, 0.f, 0.f};
#pragma unroll
    for (int j = 0; j < 4; j++) {
      const int ko = (16 * j + lr) * 32 + 8 * lg;
      short8 k0[3], k1[3];
#pragma unroll
      for (int lv = 0; lv < 3; lv++) {
        k0[lv] = *(const short8*)(&sK[lv][0][ko]);
        k1[lv] = *(const short8*)(&sK[lv][1][ko]);
      }
      // weight 1: hh
      s[j] = __builtin_amdgcn_mfma_f32_16x16x32_bf16(qf[0][0], k0[0], s[j], 0, 0, 0);
      s[j] = __builtin_amdgcn_mfma_f32_16x16x32_bf16(qf[0][1], k1[0], s[j], 0, 0, 0);
      // weight 2^-8: hm, mh
      s[j] = __builtin_amdgcn_mfma_f32_16x16x32_bf16(qf[0][0], k0[1], s[j], 0, 0, 0);
      s[j] = __builtin_amdgcn_mfma_f32_16x16x32_bf16(qf[0][1], k1[1], s[j], 0, 0, 0);
      s[j] = __builtin_amdgcn_mfma_f32_16x16x32_bf16(qf[1][0], k0[0], s[j], 0, 0, 0);
      s[j] = __builtin_amdgcn_mfma_f32_16x16x32_bf16(qf[1][1], k1[0], s[j], 0, 0, 0);
      // weight 2^-16: hl, mm, lh
      s[j] = __builtin_amdgcn_mfma_f32_16x16x32_bf16(qf[0][0], k0[2], s[j], 0, 0, 0);
      s[j] = __builtin_amdgcn_mfma_f32_16x16x32_bf16(qf[0][1], k1[2], s[j], 0, 0, 0);
      s[j] = __builtin_amdgcn_mfma_f32_16x16x32_bf16(qf[1][0], k0[1], s[j], 0, 0, 0);
      s[j] = __builtin_amdgcn_mfma_f32_16x16x32_bf16(qf[1][1], k1[1], s[j], 0, 0, 0);
      s[j] = __builtin_amdgcn_mfma_f32_16x16x32_bf16(qf[2][0], k0[0], s[j], 0, 0, 0);
      s[j] = __builtin_amdgcn_mfma_f32_16x16x32_bf16(qf[2][1], k1[0], s[j], 0, 0, 0);
    }

    // online softmax (row = q0 + 4*lg + rr, col = kb + 16*j + lr)
    const bool diag = (kt == qt);
#pragma unroll
    for (int rr = 0; rr < 4; rr++) {
      const int q = q0 + 4 * lg + rr;
      float mx = -1e30f;
#pragma unroll
      for (int j = 0; j < 4; j++) {
        float v = s[j][rr] * 0.125f;
        if (diag && (kb + 16 * j + lr > q)) v = -1e30f;
        s[j][rr] = v;
        mx = fmaxf(mx, v);
      }
      mx = fmaxf(mx, __shfl_xor(mx, 1));
      mx = fmaxf(mx, __shfl_xor(mx, 2));
      mx = fmaxf(mx, __shfl_xor(mx, 4));
      mx = fmaxf(mx, __shfl_xor(mx, 8));
      float mn = fmaxf(m[rr], mx);
      float al = expf(m[rr] - mn);
      m[rr] = mn;
      l[rr] *= al;
#pragma unroll
      for (int j = 0; j < 4; j++) Y[j][rr] *= al;
      float ps = 0.f;
#pragma unroll
      for (int j = 0; j < 4; j++) {
        float p = expf(s[j][rr] - mn);
        s[j][rr] = p;
        ps += p;
      }
      l[rr] += ps;
    }

    // P -> LDS (3-way split), barrier, then Y += P V (6 products x 2 chunks)
#pragma unroll
    for (int j = 0; j < 4; j++) {
      const int jh = j >> 1;
      const int col = 16 * (j & 1) + lr;
#pragma unroll
      for (int rr = 0; rr < 4; rr++) {
        float p = s[j][rr];
        unsigned short w0 = f2bf(p);
        float r = p - bf2f(w0);
        unsigned short w1 = f2bf(r);
        r -= bf2f(w1);
        const int o = (4 * lg + rr) * 32 + col;
        sP[0][jh][wv][o] = w0;
        sP[1][jh][wv][o] = w1;
        sP[2][jh][wv][o] = f2bf(r);
      }
    }
    __syncthreads();                  // P visible
    const int po = lr * 32 + 8 * lg;
    short8 pf[3][2];
#pragma unroll
    for (int lv = 0; lv < 3; lv++) {
      pf[lv][0] = *(const short8*)(&sP[lv][0][wv][po]);
      pf[lv][1] = *(const short8*)(&sP[lv][1][wv][po]);
    }
#pragma unroll
    for (int jd = 0; jd < 4; jd++) {
      const int vo = (16 * jd + lr) * 32 + 8 * lg;
      short8 v0[3], v1[3];
#pragma unroll
      for (int lv = 0; lv < 3; lv++) {
        v0[lv] = *(const short8*)(&sV[lv][0][vo]);
        v1[lv] = *(const short8*)(&sV[lv][1][vo]);
      }
      Y[jd] = __builtin_amdgcn_mfma_f32_16x16x32_bf16(pf[0][0], v0[0], Y[jd], 0, 0, 0);
      Y[jd] = __builtin_amdgcn_mfma_f32_16x16x32_bf16(pf[0][1], v1[0], Y[jd], 0, 0, 0);
      Y[jd] = __builtin_amdgcn_mfma_f32_16x16x32_bf16(pf[0][0], v0[1], Y[jd], 0, 0, 0);
      Y[jd] = __builtin_amdgcn_mfma_f32_16x16x32_bf16(pf[0][1], v1[1], Y[jd], 0, 0, 0);
      Y[jd] = __builtin_amdgcn_mfma_f32_16x16x32_bf16(pf[1][0], v0[0], Y[jd], 0, 0, 0);
      Y[jd] = __builtin_amdgcn_mfma_f32_16x16x32_bf16(pf[1][1], v1[0], Y[jd], 0, 0, 0);
      Y[jd] = __builtin_amdgcn_mfma_f32_16x16x32_bf16(pf[0][0], v0[2], Y[jd], 0, 0, 0);
      Y[jd] = __builtin_amdgcn_mfma_f32_16x16x32_bf16(pf[0][1], v1[2], Y[jd], 0, 0, 0);
      Y[jd] = __builtin_amdgcn_mfma_f32_16x16x32_bf16(pf[1][0], v0[1], Y[jd], 0, 0, 0);
      Y[jd] = __builtin_amdgcn_mfma_f32_16x16x32_bf16(pf[1][1], v1[1], Y[jd], 0, 0, 0);
      Y[jd] = __builtin_amdgcn_mfma_f32_16x16x32_bf16(pf[2][0], v0[0], Y[jd], 0, 0, 0);
      Y[jd] = __builtin_amdgcn_mfma_f32_16x16x32_bf16(pf[2][1], v1[0], Y[jd], 0, 0, 0);
    }
  }

  // epilogue: reduce l across the 16-lane row group, normalize, store f32
#pragma unroll
  for (int rr = 0; rr < 4; rr++) {
    float t = l[rr];
    t += __shfl_xor(t, 1); t += __shfl_xor(t, 2);
    t += __shfl_xor(t, 4); t += __shfl_xor(t, 8);
    l[rr] = 1.0f / t;
  }
#pragma unroll
  for (int jd = 0; jd < 4; jd++) {
    const int d = 16 * jd + lr;
#pragma unroll
    for (int rr = 0; rr < 4; rr++) {
      const int q = q0 + 4 * lg + rr;
      att[((size_t)(b * TSEQ + q)) * CDIM + h * DHEAD + d] = Y[jd][rr] * l[rr];
    }
  }
}

// ---------------- LayerNorm f32 -> split hi/lo bf16 (R8 proven) ----------------
__global__ __launch_bounds__(256) void ln_split_kernel(const float* __restrict__ x,
                                                       unsigned short* __restrict__ yh,
                                                       unsigned short* __restrict__ yl,
                                                       const float* __restrict__ g,
                                                       const float* __restrict__ b) {
  int n = blockIdx.x, tid = threadIdx.x;
  const float4* xr = (const float4*)(x + (size_t)n * CDIM);
  float4 v = xr[tid];
  float s = v.x + v.y + v.z + v.w;
  float ss = v.x * v.x + v.y * v.y + v.z * v.z + v.w * v.w;
  __shared__ float rs[256], rss[256];
  rs[tid] = s; rss[tid] = ss;
  __syncthreads();
  for (int o = 128; o > 0; o >>= 1) {
    if (tid < o) { rs[tid] += rs[tid + o]; rss[tid] += rss[tid + o]; }
    __syncthreads();
  }
  float m = rs[0] * (1.0f / CDIM);
  float var = rss[0] * (1.0f / CDIM) - m * m;
  float r = rsqrtf(var + 1e-5f);
  float4 gv = ((const float4*)g)[tid];
  float4 bv = ((const float4*)b)[tid];
  float o0 = (v.x - m) * r * gv.x + bv.x;
  float o1 = (v.y - m) * r * gv.y + bv.y;
  float o2 = (v.z - m) * r * gv.z + bv.z;
  float o3 = (v.w - m) * r * gv.w + bv.w;
  ushort4 hh, ll;
  hh.x = f2bf(o0); ll.x = f2bf(o0 - bf2f(hh.x));
  hh.y = f2bf(o1); ll.y = f2bf(o1 - bf2f(hh.y));
  hh.z = f2bf(o2); ll.z = f2bf(o2 - bf2f(hh.z));
  hh.w = f2bf(o3); ll.w = f2bf(o3 - bf2f(hh.w));
  ((ushort4*)(yh + (size_t)n * CDIM))[tid] = hh;
  ((ushort4*)(yl + (size_t)n * CDIM))[tid] = ll;
}

// ---------------- f32 -> split hi/lo bf16 (R8 proven) ----------------
__global__ __launch_bounds__(256) void cvt_split_kernel(const float* __restrict__ x,
                                                        unsigned short* __restrict__ yh,
                                                        unsigned short* __restrict__ yl) {
  int i = blockIdx.x * 256 + threadIdx.x;
  float4 v = ((const float4*)x)[i];
  ushort4 hh, ll;
  hh.x = f2bf(v.x); ll.x = f2bf(v.x - bf2f(hh.x));
  hh.y = f2bf(v.y); ll.y = f2bf(v.y - bf2f(hh.y));
  hh.z = f2bf(v.z); ll.z = f2bf(v.z - bf2f(hh.z));
  hh.w = f2bf(v.w); ll.w = f2bf(v.w - bf2f(hh.w));
  ((ushort4*)yh)[i] = hh;
  ((ushort4*)yl)[i] = ll;
}

// ---------------- f32 -> bf16 convert (R7 proven) ----------------
__global__ __launch_bounds__(256) void cvt_bf16_kernel(const float* __restrict__ x,
                                                       unsigned short* __restrict__ y) {
  int i = blockIdx.x * 256 + threadIdx.x;
  float4 v = ((const float4*)x)[i];
  ushort4 o;
  o.x = f2bf(v.x); o.y = f2bf(v.y); o.z = f2bf(v.z); o.w = f2bf(v.w);
  ((ushort4*)y)[i] = o;
}

// ---------------- LayerNorm f32 -> bf16 (R4 proven) ----------------
__global__ __launch_bounds__(256) void ln_bf16_kernel(const float* __restrict__ x,
                                                      unsigned short* __restrict__ y,
                                                      const float* __restrict__ g,
                                                      const float* __restrict__ b) {
  int n = blockIdx.x, tid = threadIdx.x;
  const float4* xr = (const float4*)(x + (size_t)n * CDIM);
  float4 v = xr[tid];
  float s = v.x + v.y + v.z + v.w;
  float ss = v.x * v.x + v.y * v.y + v.z * v.z + v.w * v.w;
  __shared__ float rs[256], rss[256];
  rs[tid] = s; rss[tid] = ss;
  __syncthreads();
  for (int o = 128; o > 0; o >>= 1) {
    if (tid < o) { rs[tid] += rs[tid + o]; rss[tid] += rss[tid + o]; }
    __syncthreads();
  }
  float m = rs[0] * (1.0f / CDIM);
  float var = rss[0] * (1.0f / CDIM) - m * m;
  float r = rsqrtf(var + 1e-5f);
  float4 gv = ((const float4*)g)[tid];
  float4 bv = ((const float4*)b)[tid];
  ushort4 o4;
  o4.x = f2bf((v.x - m) * r * gv.x + bv.x);
  o4.y = f2bf((v.y - m) * r * gv.y + bv.y);
  o4.z = f2bf((v.z - m) * r * gv.z + bv.z);
  o4.w = f2bf((v.w - m) * r * gv.w + bv.w);
  ((ushort4*)(y + (size_t)n * CDIM))[tid] = o4;
}

// ---------------- elementwise kernels (R7/R8 proven) ----------------
__global__ __launch_bounds__(256) void biasgelu_cvt_kernel(const float* __restrict__ in,
                                                           const float* __restrict__ bias,
                                                           unsigned short* __restrict__ out,
                                                           int Fm4) {
  int i = blockIdx.x * 256 + threadIdx.x;
  int c4 = (i & (Fm4 - 1)) << 2;
  float4 v = ((const float4*)in)[i];
  float4 b = *(const float4*)(bias + c4);
  float a0 = v.x + b.x, a1 = v.y + b.y, a2 = v.z + b.z, a3 = v.w + b.w;
  ushort4 o;
  o.x = f2bf(0.5f * a0 * (1.0f + erff(a0 * 0.70710678118654752f)));
  o.y = f2bf(0.5f * a1 * (1.0f + erff(a1 * 0.70710678118654752f)));
  o.z = f2bf(0.5f * a2 * (1.0f + erff(a2 * 0.70710678118654752f)));
  o.w = f2bf(0.5f * a3 * (1.0f + erff(a3 * 0.70710678118654752f)));
  ((ushort4*)out)[i] = o;
}

__global__ __launch_bounds__(256) void addres_kernel(float* __restrict__ x,
                                                     const float* __restrict__ t) {
  int i = blockIdx.x * 256 + threadIdx.x;
  float4 xv = ((const float4*)x)[i];
  float4 tv = ((const float4*)t)[i];
  xv.x += tv.x; xv.y += tv.y; xv.z += tv.z; xv.w += tv.w;
  ((float4*)x)[i] = xv;
}

__global__ __launch_bounds__(256) void add2_kernel(float* __restrict__ x,
                                                   const float* __restrict__ t,
                                                   const float* __restrict__ bias) {
  int i = blockIdx.x * 256 + threadIdx.x;
  int c4 = (i & (CDIM / 4 - 1)) << 2;
  float4 xv = ((const float4*)x)[i];
  float4 tv = ((const float4*)t)[i];
  float4 b = *(const float4*)(bias + c4);
  xv.x += tv.x + b.x; xv.y += tv.y + b.y; xv.z += tv.z + b.z; xv.w += tv.w + b.w;
  ((float4*)x)[i] = xv;
}

__global__ __launch_bounds__(256) void scaleadd_kernel(float* __restrict__ o,
                                                       const float* __restrict__ t,
                                                       const float* __restrict__ bias,
                                                       const float* __restrict__ rs) {
  int i = blockIdx.x * 256 + threadIdx.x;
  int m = i >> 8;
  int c4 = (i & (CDIM / 4 - 1)) << 2;
  float w = rs[m];
  float4 ov = ((const float4*)o)[i];
  float4 tv = ((const float4*)t)[i];
  float4 b = *(const float4*)(bias + c4);
  ov.x += w * (tv.x + b.x); ov.y += w * (tv.y + b.y);
  ov.z += w * (tv.z + b.z); ov.w += w * (tv.w + b.w);
  ((float4*)o)[i] = ov;
}

// ---------------- weight transpose+convert bf16 (R4 proven) ----------------
__global__ __launch_bounds__(256) void wconv_t_kernel(const float* __restrict__ W,
                                                      unsigned short* __restrict__ Wt,
                                                      int K, int N) {
  __shared__ float t[32][33];
  int n0 = blockIdx.x * 32, k0 = blockIdx.y * 32;
  int tx = threadIdx.x & 31, ty = threadIdx.x >> 5;
#pragma unroll
  for (int i = 0; i < 4; i++)
    t[ty + 8 * i][tx] = W[(size_t)(k0 + ty + 8 * i) * N + n0 + tx];
  __syncthreads();
#pragma unroll
  for (int i = 0; i < 4; i++)
    Wt[(size_t)(n0 + ty + 8 * i) * K + k0 + tx] = f2bf(t[tx][ty + 8 * i]);
}

// ---------------- weight transpose + hi/lo split (R8 proven) ----------------
__global__ __launch_bounds__(256) void wconv_split_kernel(const float* __restrict__ W,
                                                          unsigned short* __restrict__ Wh,
                                                          unsigned short* __restrict__ Wl,
                                                          int K, int N) {
  __shared__ float t[32][33];
  int n0 = blockIdx.x * 32, k0 = blockIdx.y * 32;
  int tx = threadIdx.x & 31, ty = threadIdx.x >> 5;
#pragma unroll
  for (int i = 0; i < 4; i++)
    t[ty + 8 * i][tx] = W[(size_t)(k0 + ty + 8 * i) * N + n0 + tx];
  __syncthreads();
#pragma unroll
  for (int i = 0; i < 4; i++) {
    float w = t[tx][ty + 8 * i];
    unsigned short h = f2bf(w);
    size_t o = (size_t)(n0 + ty + 8 * i) * K + k0 + tx;
    Wh[o] = h;
    Wl[o] = f2bf(w - bf2f(h));
  }
}

// ---------------- split-bf16 MFMA GEMM (R8 proven) ----------------
template <int FUSE>
__global__ __launch_bounds__(256) void gemm_split(const unsigned short* __restrict__ Ah,
                                                  const unsigned short* __restrict__ Al,
                                                  const unsigned short* __restrict__ Bth,
                                                  const unsigned short* __restrict__ Btl,
                                                  float* __restrict__ C,
                                                  unsigned short* __restrict__ Ch,
                                                  unsigned short* __restrict__ Cl,
                                                  const float* __restrict__ bias,
                                                  int M, int Nn, int K) {
  __shared__ __align__(16) unsigned short AsH[128 * 32];
  __shared__ __align__(16) unsigned short AsL[128 * 32];
  __shared__ __align__(16) unsigned short BsH[128 * 32];
  __shared__ __align__(16) unsigned short BsL[128 * 32];
  const int tid = threadIdx.x;
  const int wv = tid >> 6, ln = tid & 63;
  const int bm = blockIdx.y * 128, bn = blockIdx.x * 128;

  const size_t aoff0 = (size_t)(bm + 32 * wv + (ln >> 2)) * K + (size_t)((ln & 3) * 8);
  const size_t aoff1 = aoff0 + (size_t)16 * K;
  const size_t boff0 = (size_t)(bn + 32 * wv + (ln >> 2)) * K + (size_t)((ln & 3) * 8);
  const size_t boff1 = boff0 + (size_t)16 * K;
  const int lofs = 1024 * wv + ln * 8;

  const int wm = wv >> 1, wn = wv & 1;
  const int lr = ln & 15, lg = ln >> 4;

  f32x4 acc[4][4];
#pragma unroll
  for (int i = 0; i < 4; i++)
#pragma unroll
    for (int j = 0; j < 4; j++) acc[i][j] = (f32x4){0.f, 0.f, 0.f, 0.f};

  for (int k0 = 0; k0 < K; k0 += 32) {
    short8 rah0 = *(const short8*)(Ah + aoff0 + k0);
    short8 rah1 = *(const short8*)(Ah + aoff1 + k0);
    short8 ral0 = *(const short8*)(Al + aoff0 + k0);
    short8 ral1 = *(const short8*)(Al + aoff1 + k0);
    short8 rbh0 = *(const short8*)(Bth + boff0 + k0);
    short8 rbh1 = *(const short8*)(Bth + boff1 + k0);
    short8 rbl0 = *(const short8*)(Btl + boff0 + k0);
    short8 rbl1 = *(const short8*)(Btl + boff1 + k0);
    __syncthreads();
    *(short8*)(AsH + lofs)       = rah0;
    *(short8*)(AsH + lofs + 512) = rah1;
    *(short8*)(AsL + lofs)       = ral0;
    *(short8*)(AsL + lofs + 512) = ral1;
    *(short8*)(BsH + lofs)       = rbh0;
    *(short8*)(BsH + lofs + 512) = rbh1;
    *(short8*)(BsL + lofs)       = rbl0;
    *(short8*)(BsL + lofs + 512) = rbl1;
    __syncthreads();

    short8 afh[4], afl[4], bwh[4], bwl[4];
#pragma unroll
    for (int i = 0; i < 4; i++) {
      const int ao = (64 * wm + 16 * i + lr) * 32 + 8 * lg;
      afh[i] = *(const short8*)(AsH + ao);
      afl[i] = *(const short8*)(AsL + ao);
    }
#pragma unroll
    for (int j = 0; j < 4; j++) {
      const int bo = (64 * wn + 16 * j + lr) * 32 + 8 * lg;
      bwh[j] = *(const short8*)(BsH + bo);
      bwl[j] = *(const short8*)(BsL + bo);
    }
#pragma unroll
    for (int i = 0; i < 4; i++)
#pragma unroll
      for (int j = 0; j < 4; j++) {
        acc[i][j] = __builtin_amdgcn_mfma_f32_16x16x32_bf16(afh[i], bwh[j], acc[i][j], 0, 0, 0);
        acc[i][j] = __builtin_amdgcn_mfma_f32_16x16x32_bf16(afl[i], bwh[j], acc[i][j], 0, 0, 0);
        acc[i][j] = __builtin_amdgcn_mfma_f32_16x16x32_bf16(afh[i], bwl[j], acc[i][j], 0, 0, 0);
      }
  }

#pragma unroll
  for (int j = 0; j < 4; j++) {
    const int n = bn + 64 * wn + 16 * j + lr;
#pragma unroll
    for (int i = 0; i < 4; i++) {
#pragma unroll
      for (int rr = 0; rr < 4; rr++) {
        const int m = bm + 64 * wm + 16 * i + 4 * lg + rr;
        float v = acc[i][j][rr];
        const size_t ci = (size_t)m * Nn + n;
        if constexpr (FUSE == 1) {
          v += bias[n];
          v = 0.5f * v * (1.0f + erff(v * 0.70710678118654752f));
          unsigned short h = f2bf(v);
          Ch[ci] = h;
          Cl[ci] = f2bf(v - bf2f(h));
        } else {
          C[ci] = v;
        }
      }
    }
  }
}

// ---------------- bf16 MFMA GEMM (R4/R7 proven; MoE + head) ----------------
__global__ __launch_bounds__(256) void gemm_bf16(const unsigned short* __restrict__ A,
                                                 const unsigned short* __restrict__ Bt,
                                                 float* __restrict__ C,
                                                 int M, int Nn, int K) {
  __shared__ __align__(16) unsigned short As[128 * 32];
  __shared__ __align__(16) unsigned short Bs[128 * 32];
  const int tid = threadIdx.x;
  const int wv = tid >> 6, ln = tid & 63;
  const int bm = blockIdx.y * 128, bn = blockIdx.x * 128;

  const size_t aoff0 = (size_t)(bm + 32 * wv + (ln >> 2)) * K + (size_t)((ln & 3) * 8);
  const size_t aoff1 = aoff0 + (size_t)16 * K;
  const size_t boff0 = (size_t)(bn + 32 * wv + (ln >> 2)) * K + (size_t)((ln & 3) * 8);
  const size_t boff1 = boff0 + (size_t)16 * K;
  const int lofs = 1024 * wv + ln * 8;

  const int wm = wv >> 1, wn = wv & 1;
  const int lr = ln & 15, lg = ln >> 4;

  f32x4 acc[4][4];
#pragma unroll
  for (int i = 0; i < 4; i++)
#pragma unroll
    for (int j = 0; j < 4; j++) acc[i][j] = (f32x4){0.f, 0.f, 0.f, 0.f};

  for (int k0 = 0; k0 < K; k0 += 32) {
    short8 ra0 = *(const short8*)(A + aoff0 + k0);
    short8 ra1 = *(const short8*)(A + aoff1 + k0);
    short8 rb0 = *(const short8*)(Bt + boff0 + k0);
    short8 rb1 = *(const short8*)(Bt + boff1 + k0);
    __syncthreads();
    *(short8*)(As + lofs)       = ra0;
    *(short8*)(As + lofs + 512) = ra1;
    *(short8*)(Bs + lofs)       = rb0;
    *(short8*)(Bs + lofs + 512) = rb1;
    __syncthreads();

    short8 af[4], bw[4];
#pragma unroll
    for (int i = 0; i < 4; i++)
      af[i] = *(const short8*)(As + ((64 * wm + 16 * i + lr) * 32 + 8 * lg));
#pragma unroll
    for (int j = 0; j < 4; j++)
      bw[j] = *(const short8*)(Bs + ((64 * wn + 16 * j + lr) * 32 + 8 * lg));
#pragma unroll
    for (int i = 0; i < 4; i++)
#pragma unroll
      for (int j = 0; j < 4; j++)
        acc[i][j] = __builtin_amdgcn_mfma_f32_16x16x32_bf16(af[i], bw[j], acc[i][j], 0, 0, 0);
  }

#pragma unroll
  for (int j = 0; j < 4; j++) {
    const int n = bn + 64 * wn + 16 * j + lr;
#pragma unroll
    for (int i = 0; i < 4; i++) {
#pragma unroll
      for (int r = 0; r < 4; r++) {
        const int m = bm + 64 * wm + 16 * i + 4 * lg + r;
        C[(size_t)m * Nn + n] = acc[i][j][r];
      }
    }
  }
}

// ---------------- router (R0 proven) ----------------
__global__ __launch_bounds__(64) void router_kernel(const float* __restrict__ x,
                                                    const float* __restrict__ rw,
                                                    float* __restrict__ maskT) {
  int n = blockIdx.x, lane = threadIdx.x;
  const float* xr = x + (size_t)n * CDIM;
  float acc[NEXP] = {};
  for (int i = 0; i < CDIM / 64; i++) {
    int c = lane + 64 * i;
    float xv = xr[c];
    const float* r = rw + (size_t)c * NEXP;
#pragma unroll
    for (int e = 0; e < NEXP; e++) acc[e] += xv * r[e];
  }
  for (int m = 32; m >= 1; m >>= 1)
#pragma unroll
    for (int e = 0; e < NEXP; e++) acc[e] += __shfl_xor(acc[e], m);
  if (lane == 0) {
    float mx = acc[0];
#pragma unroll
    for (int e = 1; e < NEXP; e++) mx = fmaxf(mx, acc[e]);
    float p[NEXP];
#pragma unroll
    for (int e = 0; e < NEXP; e++) p[e] = expf(acc[e] - mx);
    int i1 = 0;
#pragma unroll
    for (int e = 1; e < NEXP; e++) if (p[e] > p[i1]) i1 = e;
    int i2 = (i1 == 0) ? 1 : 0;
#pragma unroll
    for (int e = 0; e < NEXP; e++) if (e != i1 && p[e] > p[i2]) i2 = e;
    float denom = p[i1] + p[i2];
    float w1 = p[i1] / denom, w2 = p[i2] / denom;
#pragma unroll
    for (int e = 0; e < NEXP; e++) maskT[(size_t)e * NTOK + n] = 0.0f;
    maskT[(size_t)i1 * NTOK + n] = w1;
    maskT[(size_t)i2 * NTOK + n] = w2;
  }
}

extern "C" void kernel_launch(void* const* d_in, const int* in_sizes, int n_in,
                              void* d_out, int out_size, void* d_ws, size_t ws_size,
                              hipStream_t stream) {
  const int*   idx      = (const int*)d_in[0];
  const float* tok_emb  = (const float*)d_in[1];
  const float* ln1_g    = (const float*)d_in[2];
  const float* ln1_b    = (const float*)d_in[3];
  const float* ln2_g    = (const float*)d_in[4];
  const float* ln2_b    = (const float*)d_in[5];
  const float* qkv_w    = (const float*)d_in[6];
  const float* proj_w   = (const float*)d_in[7];
  const float* ff_w1    = (const float*)d_in[8];
  const float* ff_b1    = (const float*)d_in[9];
  const float* ff_w2    = (const float*)d_in[10];
  const float* ff_b2    = (const float*)d_in[11];
  const float* router_w = (const float*)d_in[12];
  const float* exp_w1   = (const float*)d_in[13];
  const float* exp_b1   = (const float*)d_in[14];
  const float* exp_w2   = (const float*)d_in[15];
  const float* exp_b2   = (const float*)d_in[16];
  const float* lnf_g    = (const float*)d_in[17];
  const float* lnf_b    = (const float*)d_in[18];
  const float* head_w   = (const float*)d_in[19];
  float* out = (float*)d_out;

  // ---- workspace layout (~143.5 MB < R0's proven 168 MB) ----
  const size_t NC = (size_t)NTOK * CDIM;
  char* w = (char*)d_ws;
  float* x  = (float*)w;                 w += NC * 4;                  // 16.78 MB
  unsigned short* S1 = (unsigned short*)w; w += NC * 4;                // 2 slots
  float* Q  = (float*)w;                 w += (size_t)NTOK * C3 * 4;   // 50.33 MB
  float* C3r = (float*)w;                w += NC * 4;                  // 2 slots
  unsigned short* WS = (unsigned short*)w; w += NC * 4;                // 2 slots
  unsigned short* EX = (unsigned short*)w; w += NC * 6;                // 3 slots (25.2MB)
  float* maskT = (float*)w;              w += (size_t)NEXP * NTOK * 4;
  float* ct = (float*)w;                 w += (size_t)TSEQ * 32 * 4;
  float* st = (float*)w;                 w += (size_t)TSEQ * 32 * 4;

  // trunk aliases
  unsigned short* xh = S1;
  unsigned short* xl = S1 + NC;
  unsigned short* Wh = WS;
  unsigned short* Wl = WS + NC;
  float* qkvf = Q;
  // attention-phase aliases (9 slots: S1 x2, C3r x2, WS x2, EX x3)
  unsigned short* Qh_s = S1;
  unsigned short* Qm_s = S1 + NC;
  unsigned short* Ql_s = EX;
  unsigned short* Kh_s = (unsigned short*)C3r;
  unsigned short* Km_s = (unsigned short*)C3r + NC;
  unsigned short* Kl_s = EX + NC;
  unsigned short* Vth_s = WS;
  unsigned short* Vtm_s = WS + NC;
  unsigned short* Vtl_s = EX + 2 * NC;
  float* att_f = Q;                                    // qkvf dead after prep
  // FF aliases
  unsigned short* hh = (unsigned short*)Q;
  unsigned short* hl = (unsigned short*)Q + (size_t)NTOK * FFDIM;
  float* tmpS1 = (float*)S1;
  float* projf = C3r;
  // MoE aliases
  unsigned short* x_bf    = S1;
  unsigned short* hmoe_bf = S1 + NC;
  float* hmoe_f32 = C3r;
  float* tmp2     = Q;
  float* moe_out  = x;
  unsigned short* wt_s = WS;
  // head aliases
  unsigned short* xn_bf   = S1;
  unsigned short* wt_head = (unsigned short*)Q;        // spans Q + C3r (67.1MB)

  embed_kernel<<<NTOK, 256, 0, stream>>>(idx, tok_emb, x);
  rope_table_kernel<<<TSEQ, 32, 0, stream>>>(ct, st);

  for (int l = 0; l < LAYERS; l++) {
    // --- attention sublayer ---
    ln_split_kernel<<<NTOK, 256, 0, stream>>>(x, xh, xl, ln1_g + l * CDIM, ln1_b + l * CDIM);
    wconv_split_kernel<<<dim3(C3 / 32, CDIM / 32), 256, 0, stream>>>(
        qkv_w + (size_t)l * CDIM * C3, Wh, Wl, CDIM, C3);
    gemm_split<0><<<dim3(C3 / 128, NTOK / 128), 256, 0, stream>>>(
        xh, xl, Wh, Wl, qkvf, nullptr, nullptr, nullptr, NTOK, C3, CDIM);
    qkv_prep_kernel<<<dim3(TSEQ / 64, HEADS, 8), 256, 0, stream>>>(
        qkvf, ct, st, Qh_s, Qm_s, Ql_s, Kh_s, Km_s, Kl_s, Vth_s, Vtm_s, Vtl_s);
    flash_attn_kernel<<<dim3(TSEQ / 64, HEADS, 8), 256, 0, stream>>>(
        Qh_s, Qm_s, Ql_s, Kh_s, Km_s, Kl_s, Vth_s, Vtm_s, Vtl_s, att_f);
    cvt_split_kernel<<<(NC / 4) / 256, 256, 0, stream>>>(att_f, xh, xl);
    wconv_split_kernel<<<dim3(CDIM / 32, CDIM / 32), 256, 0, stream>>>(
        proj_w + (size_t)l * CDIM * CDIM, Wh, Wl, CDIM, CDIM);
    gemm_split<0><<<dim3(CDIM / 128, NTOK / 128), 256, 0, stream>>>(
        xh, xl, Wh, Wl, projf, nullptr, nullptr, nullptr, NTOK, CDIM, CDIM);
    addres_kernel<<<(NC / 4) / 256, 256, 0, stream>>>(x, projf);
    // --- FF sublayer ---
    ln_split_kernel<<<NTOK, 256, 0, stream>>>(x, xh, xl, ln2_g + l * CDIM, ln2_b + l * CDIM);
    wconv_split_kernel<<<dim3(FFDIM / 32, CDIM / 32), 256, 0, stream>>>(
        ff_w1 + (size_t)l * CDIM * FFDIM, Wh, Wl, CDIM, FFDIM);
    gemm_split<1><<<dim3(FFDIM / 128, NTOK / 128), 256, 0, stream>>>(
        xh, xl, Wh, Wl, nullptr, hh, hl, ff_b1 + (size_t)l * FFDIM, NTOK, FFDIM, CDIM);
    wconv_split_kernel<<<dim3(CDIM / 32, FFDIM / 32), 256, 0, stream>>>(
        ff_w2 + (size_t)l * FFDIM * CDIM, Wh, Wl, FFDIM, CDIM);
    gemm_split<0><<<dim3(CDIM / 128, NTOK / 128), 256, 0, stream>>>(
        hh, hl, Wh, Wl, tmpS1, nullptr, nullptr, nullptr, NTOK, CDIM, FFDIM);
    add2_kernel<<<(NC / 4) / 256, 256, 0, stream>>>(x, tmpS1, ff_b2 + (size_t)l * CDIM);
  }

  // --- router on trunk x, then MoE bf16 (R7 proven) ---
  router_kernel<<<NTOK, 64, 0, stream>>>(x, router_w, maskT);
  cvt_bf16_kernel<<<(NC / 4) / 256, 256, 0, stream>>>(x, x_bf);
  hipMemsetAsync(moe_out, 0, NC * sizeof(float), stream);
  for (int e = 0; e < NEXP; e++) {
    wconv_t_kernel<<<dim3(DEXP / 32, CDIM / 32), 256, 0, stream>>>(
        exp_w1 + (size_t)e * CDIM * DEXP, wt_s, CDIM, DEXP);
    gemm_bf16<<<dim3(DEXP / 128, NTOK / 128), 256, 0, stream>>>(
        x_bf, wt_s, hmoe_f32, NTOK, DEXP, CDIM);
    biasgelu_cvt_kernel<<<((int)(NC / 4)) / 256, 256, 0, stream>>>(
        hmoe_f32, exp_b1 + (size_t)e * DEXP, hmoe_bf, DEXP / 4);
    wconv_t_kernel<<<dim3(CDIM / 32, DEXP / 32), 256, 0, stream>>>(
        exp_w2 + (size_t)e * DEXP * CDIM, wt_s, DEXP, CDIM);
    gemm_bf16<<<dim3(CDIM / 128, NTOK / 128), 256, 0, stream>>>(
        hmoe_bf, wt_s, tmp2, NTOK, CDIM, DEXP);
    scaleadd_kernel<<<((int)(NC / 4)) / 256, 256, 0, stream>>>(
        moe_out, tmp2, exp_b2 + (size_t)e * CDIM, maskT + (size_t)e * NTOK);
  }

  // --- head: bf16 (R4/R7 proven) ---
  ln_bf16_kernel<<<NTOK, 256, 0, stream>>>(moe_out, xn_bf, lnf_g, lnf_b);
  wconv_t_kernel<<<dim3(VOCAB / 32, CDIM / 32), 256, 0, stream>>>(head_w, wt_head, CDIM, VOCAB);
  gemm_bf16<<<dim3(VOCAB / 128, NTOK / 128), 256, 0, stream>>>(
      xn_bf, wt_head, out, NTOK, VOCAB, CDIM);
}

// Round 14
// 2864.889 us; speedup vs baseline: 4.1602x; 1.0333x over previous
//
#include <hip/hip_runtime.h>
#include <math.h>

// MoE-GPT forward, round 14: R13 + (1) XCD-chunked block swizzle in all GEMMs
// (T1, grids all %8==0), (2) re-fused epilogues (vindicated by R5===R6:
// proj residual, FF2 residual+bias, MoE gelu / rowscale-add, flash split-out),
// (3) dead elementwise kernels removed. Arithmetic identical to R13.

#define NTOK  4096
#define CDIM  1024
#define HEADS 16
#define DHEAD 64
#define LAYERS 3
#define NEXP  8
#define DEXP  1024
#define TSEQ  512
#define FFDIM 4096
#define VOCAB 32000
#define C3    3072

typedef __attribute__((ext_vector_type(8))) short short8;
typedef __attribute__((ext_vector_type(4))) float f32x4;

__device__ __forceinline__ unsigned short f2bf(float f) {
  unsigned int u = __builtin_bit_cast(unsigned int, f);
  return (unsigned short)((u + 0x7fffu + ((u >> 16) & 1u)) >> 16);  // RNE
}
__device__ __forceinline__ float bf2f(unsigned short h) {
  return __builtin_bit_cast(float, ((unsigned int)h) << 16);
}

// ---------------- embedding gather ----------------
__global__ __launch_bounds__(256) void embed_kernel(const int* __restrict__ idx,
                                                    const float* __restrict__ emb,
                                                    float* __restrict__ x) {
  int i = blockIdx.x * 256 + threadIdx.x;
  int n = i >> 8, c4 = i & 255;
  const float4* src = (const float4*)(emb + (size_t)idx[n] * CDIM);
  ((float4*)(x + (size_t)n * CDIM))[c4] = src[c4];
}

// ---------------- RoPE cos/sin table [T][32] ----------------
__global__ void rope_table_kernel(float* __restrict__ ct, float* __restrict__ st) {
  int t = blockIdx.x, p = threadIdx.x;
  float inv = powf(10000.0f, -(float)p / 32.0f);
  float ang = (float)t * inv;
  ct[t * 32 + p] = cosf(ang);
  st[t * 32 + p] = sinf(ang);
}

// ---------------- qkv prep: RoPE + 3-way split + head-major relayout (R13 proven) ----------------
__global__ __launch_bounds__(256) void qkv_prep_kernel(
    const float* __restrict__ qkv, const float* __restrict__ ct,
    const float* __restrict__ st,
    unsigned short* __restrict__ Qh, unsigned short* __restrict__ Qm,
    unsigned short* __restrict__ Ql,
    unsigned short* __restrict__ Kh, unsigned short* __restrict__ Km,
    unsigned short* __restrict__ Kl,
    unsigned short* __restrict__ Vth, unsigned short* __restrict__ Vtm,
    unsigned short* __restrict__ Vtl) {
  __shared__ unsigned short sVh[64 * 64], sVm[64 * 64], sVl[64 * 64];  // [d][t]
  const int tid = threadIdx.x;
  const int tt0 = blockIdx.x * 64, h = blockIdx.y, b = blockIdx.z;
  const int bh = b * HEADS + h;
#pragma unroll
  for (int u = 0; u < 8; u++) {
    int pidx = tid + u * 256;
    int tl = pidx >> 5, p = pidx & 31;
    int t = tt0 + tl;
    size_t nb = ((size_t)(b * TSEQ + t)) * C3 + h * DHEAD;
    float c0 = ct[t * 32 + p], s0 = st[t * 32 + p];
    size_t ob = ((size_t)bh * TSEQ + t) * 64;
    float a = qkv[nb + p], bb = qkv[nb + p + 32];
    float lo = a * c0 - bb * s0, hi = bb * c0 + a * s0;
    unsigned short w0, w1;
    float r;
    w0 = f2bf(lo); r = lo - bf2f(w0); w1 = f2bf(r); r -= bf2f(w1);
    Qh[ob + p] = w0; Qm[ob + p] = w1; Ql[ob + p] = f2bf(r);
    w0 = f2bf(hi); r = hi - bf2f(w0); w1 = f2bf(r); r -= bf2f(w1);
    Qh[ob + p + 32] = w0; Qm[ob + p + 32] = w1; Ql[ob + p + 32] = f2bf(r);
    a = qkv[nb + CDIM + p]; bb = qkv[nb + CDIM + p + 32];
    lo = a * c0 - bb * s0; hi = bb * c0 + a * s0;
    w0 = f2bf(lo); r = lo - bf2f(w0); w1 = f2bf(r); r -= bf2f(w1);
    Kh[ob + p] = w0; Km[ob + p] = w1; Kl[ob + p] = f2bf(r);
    w0 = f2bf(hi); r = hi - bf2f(w0); w1 = f2bf(r); r -= bf2f(w1);
    Kh[ob + p + 32] = w0; Km[ob + p + 32] = w1; Kl[ob + p + 32] = f2bf(r);
  }
#pragma unroll
  for (int u = 0; u < 4; u++) {
    int vidx = tid + u * 256;
    int tl = vidx >> 4, d4 = (vidx & 15) * 4;
    int t = tt0 + tl;
    float4 v = *(const float4*)(qkv + ((size_t)(b * TSEQ + t)) * C3 + 2 * CDIM + h * DHEAD + d4);
    float vv[4] = {v.x, v.y, v.z, v.w};
#pragma unroll
    for (int j = 0; j < 4; j++) {
      unsigned short w0 = f2bf(vv[j]);
      float r = vv[j] - bf2f(w0);
      unsigned short w1 = f2bf(r);
      r -= bf2f(w1);
      sVh[(d4 + j) * 64 + tl] = w0;
      sVm[(d4 + j) * 64 + tl] = w1;
      sVl[(d4 + j) * 64 + tl] = f2bf(r);
    }
  }
  __syncthreads();
#pragma unroll
  for (int u = 0; u < 2; u++) {
    int idx = tid + u * 256;
    int d = idx >> 3, seg = (idx & 7) * 8;
    size_t go = ((size_t)bh * 64 + d) * TSEQ + tt0 + seg;
    *(short8*)(Vth + go) = *(const short8*)(sVh + d * 64 + seg);
    *(short8*)(Vtm + go) = *(const short8*)(sVm + d * 64 + seg);
    *(short8*)(Vtl + go) = *(const short8*)(sVl + d * 64 + seg);
  }
}

// ---------------- flash attention, 3-way split (R13 proven), split output ----------------
__global__ __launch_bounds__(256) void flash_attn_kernel(
    const unsigned short* __restrict__ Qh, const unsigned short* __restrict__ Qm,
    const unsigned short* __restrict__ Ql,
    const unsigned short* __restrict__ Kh, const unsigned short* __restrict__ Km,
    const unsigned short* __restrict__ Kl,
    const unsigned short* __restrict__ Vth, const unsigned short* __restrict__ Vtm,
    const unsigned short* __restrict__ Vtl,
    unsigned short* __restrict__ ath, unsigned short* __restrict__ atl) {
  __shared__ __align__(16) unsigned short sK[3][2][64 * 32];
  __shared__ __align__(16) unsigned short sV[3][2][64 * 32];
  __shared__ __align__(16) unsigned short sP[3][2][4][16 * 32];
  const int tid = threadIdx.x;
  const int wv = tid >> 6, ln = tid & 63;
  const int qt = blockIdx.x, h = blockIdx.y, b = blockIdx.z;
  const int bh = b * HEADS + h;
  const int lr = ln & 15, lg = ln >> 4;
  const int q0 = qt * 64 + wv * 16;

  const size_t qoff = ((size_t)bh * TSEQ + q0 + lr) * 64 + 8 * lg;
  short8 qf[3][2];
  qf[0][0] = *(const short8*)(Qh + qoff); qf[0][1] = *(const short8*)(Qh + qoff + 32);
  qf[1][0] = *(const short8*)(Qm + qoff); qf[1][1] = *(const short8*)(Qm + qoff + 32);
  qf[2][0] = *(const short8*)(Ql + qoff); qf[2][1] = *(const short8*)(Ql + qoff + 32);

  f32x4 Y[4];
#pragma unroll
  for (int j = 0; j < 4; j++) Y[j] = (f32x4){0.f, 0.f, 0.f, 0.f};
  float m[4] = {-1e30f, -1e30f, -1e30f, -1e30f};
  float l[4] = {0.f, 0.f, 0.f, 0.f};

  const int r0 = tid >> 3, sg = (tid & 7) * 8;
  const int half = sg >> 5, soff = (sg & 31);

  for (int kt = 0; kt <= qt; kt++) {
    const int kb = kt * 64;
    short8 stg[12];
#pragma unroll
    for (int u = 0; u < 2; u++) {
      int row = r0 + 32 * u;
      size_t gk = ((size_t)bh * TSEQ + kb + row) * 64 + sg;
      size_t gv = ((size_t)bh * 64 + row) * TSEQ + kb + sg;
      stg[u * 6 + 0] = *(const short8*)(Kh + gk);
      stg[u * 6 + 1] = *(const short8*)(Km + gk);
      stg[u * 6 + 2] = *(const short8*)(Kl + gk);
      stg[u * 6 + 3] = *(const short8*)(Vth + gv);
      stg[u * 6 + 4] = *(const short8*)(Vtm + gv);
      stg[u * 6 + 5] = *(const short8*)(Vtl + gv);
    }
    __syncthreads();
#pragma unroll
    for (int u = 0; u < 2; u++) {
      int off = (r0 + 32 * u) * 32 + soff;
      *(short8*)(&sK[0][half][off]) = stg[u * 6 + 0];
      *(short8*)(&sK[1][half][off]) = stg[u * 6 + 1];
      *(short8*)(&sK[2][half][off]) = stg[u * 6 + 2];
      *(short8*)(&sV[0][half][off]) = stg[u * 6 + 3];
      *(short8*)(&sV[1][half][off]) = stg[u * 6 + 4];
      *(short8*)(&sV[2][half][off]) = stg[u * 6 + 5];
    }
    __syncthreads();

    f32x4 s[4];
#pragma unroll
    for (int j = 0; j < 4; j++) s[j] = (f32x4){0.f, 0.f, 0.f, 0.f};
#pragma unroll
    for (int j = 0; j < 4; j++) {
      const int ko = (16 * j + lr) * 32 + 8 * lg;
      short8 k0[3], k1[3];
#pragma unroll
      for (int lv = 0; lv < 3; lv++) {
        k0[lv] = *(const short8*)(&sK[lv][0][ko]);
        k1[lv] = *(const short8*)(&sK[lv][1][ko]);
      }
      s[j] = __builtin_amdgcn_mfma_f32_16x16x32_bf16(qf[0][0], k0[0], s[j], 0, 0, 0);
      s[j] = __builtin_amdgcn_mfma_f32_16x16x32_bf16(qf[0][1], k1[0], s[j], 0, 0, 0);
      s[j] = __builtin_amdgcn_mfma_f32_16x16x32_bf16(qf[0][0], k0[1], s[j], 0, 0, 0);
      s[j] = __builtin_amdgcn_mfma_f32_16x16x32_bf16(qf[0][1], k1[1], s[j], 0, 0, 0);
      s[j] = __builtin_amdgcn_mfma_f32_16x16x32_bf16(qf[1][0], k0[0], s[j], 0, 0, 0);
      s[j] = __builtin_amdgcn_mfma_f32_16x16x32_bf16(qf[1][1], k1[0], s[j], 0, 0, 0);
      s[j] = __builtin_amdgcn_mfma_f32_16x16x32_bf16(qf[0][0], k0[2], s[j], 0, 0, 0);
      s[j] = __builtin_amdgcn_mfma_f32_16x16x32_bf16(qf[0][1], k1[2], s[j], 0, 0, 0);
      s[j] = __builtin_amdgcn_mfma_f32_16x16x32_bf16(qf[1][0], k0[1], s[j], 0, 0, 0);
      s[j] = __builtin_amdgcn_mfma_f32_16x16x32_bf16(qf[1][1], k1[1], s[j], 0, 0, 0);
      s[j] = __builtin_amdgcn_mfma_f32_16x16x32_bf16(qf[2][0], k0[0], s[j], 0, 0, 0);
      s[j] = __builtin_amdgcn_mfma_f32_16x16x32_bf16(qf[2][1], k1[0], s[j], 0, 0, 0);
    }

    const bool diag = (kt == qt);
#pragma unroll
    for (int rr = 0; rr < 4; rr++) {
      const int q = q0 + 4 * lg + rr;
      float mx = -1e30f;
#pragma unroll
      for (int j = 0; j < 4; j++) {
        float v = s[j][rr] * 0.125f;
        if (diag && (kb + 16 * j + lr > q)) v = -1e30f;
        s[j][rr] = v;
        mx = fmaxf(mx, v);
      }
      mx = fmaxf(mx, __shfl_xor(mx, 1));
      mx = fmaxf(mx, __shfl_xor(mx, 2));
      mx = fmaxf(mx, __shfl_xor(mx, 4));
      mx = fmaxf(mx, __shfl_xor(mx, 8));
      float mn = fmaxf(m[rr], mx);
      float al = expf(m[rr] - mn);
      m[rr] = mn;
      l[rr] *= al;
#pragma unroll
      for (int j = 0; j < 4; j++) Y[j][rr] *= al;
      float ps = 0.f;
#pragma unroll
      for (int j = 0; j < 4; j++) {
        float p = expf(s[j][rr] - mn);
        s[j][rr] = p;
        ps += p;
      }
      l[rr] += ps;
    }

#pragma unroll
    for (int j = 0; j < 4; j++) {
      const int jh = j >> 1;
      const int col = 16 * (j & 1) + lr;
#pragma unroll
      for (int rr = 0; rr < 4; rr++) {
        float p = s[j][rr];
        unsigned short w0 = f2bf(p);
        float r = p - bf2f(w0);
        unsigned short w1 = f2bf(r);
        r -= bf2f(w1);
        const int o = (4 * lg + rr) * 32 + col;
        sP[0][jh][wv][o] = w0;
        sP[1][jh][wv][o] = w1;
        sP[2][jh][wv][o] = f2bf(r);
      }
    }
    __syncthreads();
    const int po = lr * 32 + 8 * lg;
    short8 pf[3][2];
#pragma unroll
    for (int lv = 0; lv < 3; lv++) {
      pf[lv][0] = *(const short8*)(&sP[lv][0][wv][po]);
      pf[lv][1] = *(const short8*)(&sP[lv][1][wv][po]);
    }
#pragma unroll
    for (int jd = 0; jd < 4; jd++) {
      const int vo = (16 * jd + lr) * 32 + 8 * lg;
      short8 v0[3], v1[3];
#pragma unroll
      for (int lv = 0; lv < 3; lv++) {
        v0[lv] = *(const short8*)(&sV[lv][0][vo]);
        v1[lv] = *(const short8*)(&sV[lv][1][vo]);
      }
      Y[jd] = __builtin_amdgcn_mfma_f32_16x16x32_bf16(pf[0][0], v0[0], Y[jd], 0, 0, 0);
      Y[jd] = __builtin_amdgcn_mfma_f32_16x16x32_bf16(pf[0][1], v1[0], Y[jd], 0, 0, 0);
      Y[jd] = __builtin_amdgcn_mfma_f32_16x16x32_bf16(pf[0][0], v0[1], Y[jd], 0, 0, 0);
      Y[jd] = __builtin_amdgcn_mfma_f32_16x16x32_bf16(pf[0][1], v1[1], Y[jd], 0, 0, 0);
      Y[jd] = __builtin_amdgcn_mfma_f32_16x16x32_bf16(pf[1][0], v0[0], Y[jd], 0, 0, 0);
      Y[jd] = __builtin_amdgcn_mfma_f32_16x16x32_bf16(pf[1][1], v1[0], Y[jd], 0, 0, 0);
      Y[jd] = __builtin_amdgcn_mfma_f32_16x16x32_bf16(pf[0][0], v0[2], Y[jd], 0, 0, 0);
      Y[jd] = __builtin_amdgcn_mfma_f32_16x16x32_bf16(pf[0][1], v1[2], Y[jd], 0, 0, 0);
      Y[jd] = __builtin_amdgcn_mfma_f32_16x16x32_bf16(pf[1][0], v0[1], Y[jd], 0, 0, 0);
      Y[jd] = __builtin_amdgcn_mfma_f32_16x16x32_bf16(pf[1][1], v1[1], Y[jd], 0, 0, 0);
      Y[jd] = __builtin_amdgcn_mfma_f32_16x16x32_bf16(pf[2][0], v0[0], Y[jd], 0, 0, 0);
      Y[jd] = __builtin_amdgcn_mfma_f32_16x16x32_bf16(pf[2][1], v1[0], Y[jd], 0, 0, 0);
    }
  }

  // epilogue: normalize + hi/lo split store (replaces f32 store + cvt_split)
#pragma unroll
  for (int rr = 0; rr < 4; rr++) {
    float t = l[rr];
    t += __shfl_xor(t, 1); t += __shfl_xor(t, 2);
    t += __shfl_xor(t, 4); t += __shfl_xor(t, 8);
    l[rr] = 1.0f / t;
  }
#pragma unroll
  for (int jd = 0; jd < 4; jd++) {
    const int d = 16 * jd + lr;
#pragma unroll
    for (int rr = 0; rr < 4; rr++) {
      const int q = q0 + 4 * lg + rr;
      float v = Y[jd][rr] * l[rr];
      unsigned short w0 = f2bf(v);
      const size_t ci = ((size_t)(b * TSEQ + q)) * CDIM + h * DHEAD + d;
      ath[ci] = w0;
      atl[ci] = f2bf(v - bf2f(w0));
    }
  }
}

// ---------------- LayerNorm f32 -> split hi/lo bf16 (R8 proven) ----------------
__global__ __launch_bounds__(256) void ln_split_kernel(const float* __restrict__ x,
                                                       unsigned short* __restrict__ yh,
                                                       unsigned short* __restrict__ yl,
                                                       const float* __restrict__ g,
                                                       const float* __restrict__ b) {
  int n = blockIdx.x, tid = threadIdx.x;
  const float4* xr = (const float4*)(x + (size_t)n * CDIM);
  float4 v = xr[tid];
  float s = v.x + v.y + v.z + v.w;
  float ss = v.x * v.x + v.y * v.y + v.z * v.z + v.w * v.w;
  __shared__ float rs[256], rss[256];
  rs[tid] = s; rss[tid] = ss;
  __syncthreads();
  for (int o = 128; o > 0; o >>= 1) {
    if (tid < o) { rs[tid] += rs[tid + o]; rss[tid] += rss[tid + o]; }
    __syncthreads();
  }
  float m = rs[0] * (1.0f / CDIM);
  float var = rss[0] * (1.0f / CDIM) - m * m;
  float r = rsqrtf(var + 1e-5f);
  float4 gv = ((const float4*)g)[tid];
  float4 bv = ((const float4*)b)[tid];
  float o0 = (v.x - m) * r * gv.x + bv.x;
  float o1 = (v.y - m) * r * gv.y + bv.y;
  float o2 = (v.z - m) * r * gv.z + bv.z;
  float o3 = (v.w - m) * r * gv.w + bv.w;
  ushort4 hh, ll;
  hh.x = f2bf(o0); ll.x = f2bf(o0 - bf2f(hh.x));
  hh.y = f2bf(o1); ll.y = f2bf(o1 - bf2f(hh.y));
  hh.z = f2bf(o2); ll.z = f2bf(o2 - bf2f(hh.z));
  hh.w = f2bf(o3); ll.w = f2bf(o3 - bf2f(hh.w));
  ((ushort4*)(yh + (size_t)n * CDIM))[tid] = hh;
  ((ushort4*)(yl + (size_t)n * CDIM))[tid] = ll;
}

// ---------------- f32 -> bf16 convert (R7 proven) ----------------
__global__ __launch_bounds__(256) void cvt_bf16_kernel(const float* __restrict__ x,
                                                       unsigned short* __restrict__ y) {
  int i = blockIdx.x * 256 + threadIdx.x;
  float4 v = ((const float4*)x)[i];
  ushort4 o;
  o.x = f2bf(v.x); o.y = f2bf(v.y); o.z = f2bf(v.z); o.w = f2bf(v.w);
  ((ushort4*)y)[i] = o;
}

// ---------------- LayerNorm f32 -> bf16 (R4 proven) ----------------
__global__ __launch_bounds__(256) void ln_bf16_kernel(const float* __restrict__ x,
                                                      unsigned short* __restrict__ y,
                                                      const float* __restrict__ g,
                                                      const float* __restrict__ b) {
  int n = blockIdx.x, tid = threadIdx.x;
  const float4* xr = (const float4*)(x + (size_t)n * CDIM);
  float4 v = xr[tid];
  float s = v.x + v.y + v.z + v.w;
  float ss = v.x * v.x + v.y * v.y + v.z * v.z + v.w * v.w;
  __shared__ float rs[256], rss[256];
  rs[tid] = s; rss[tid] = ss;
  __syncthreads();
  for (int o = 128; o > 0; o >>= 1) {
    if (tid < o) { rs[tid] += rs[tid + o]; rss[tid] += rss[tid + o]; }
    __syncthreads();
  }
  float m = rs[0] * (1.0f / CDIM);
  float var = rss[0] * (1.0f / CDIM) - m * m;
  float r = rsqrtf(var + 1e-5f);
  float4 gv = ((const float4*)g)[tid];
  float4 bv = ((const float4*)b)[tid];
  ushort4 o4;
  o4.x = f2bf((v.x - m) * r * gv.x + bv.x);
  o4.y = f2bf((v.y - m) * r * gv.y + bv.y);
  o4.z = f2bf((v.z - m) * r * gv.z + bv.z);
  o4.w = f2bf((v.w - m) * r * gv.w + bv.w);
  ((ushort4*)(y + (size_t)n * CDIM))[tid] = o4;
}

// ---------------- weight transpose+convert bf16 (R4 proven) ----------------
__global__ __launch_bounds__(256) void wconv_t_kernel(const float* __restrict__ W,
                                                      unsigned short* __restrict__ Wt,
                                                      int K, int N) {
  __shared__ float t[32][33];
  int n0 = blockIdx.x * 32, k0 = blockIdx.y * 32;
  int tx = threadIdx.x & 31, ty = threadIdx.x >> 5;
#pragma unroll
  for (int i = 0; i < 4; i++)
    t[ty + 8 * i][tx] = W[(size_t)(k0 + ty + 8 * i) * N + n0 + tx];
  __syncthreads();
#pragma unroll
  for (int i = 0; i < 4; i++)
    Wt[(size_t)(n0 + ty + 8 * i) * K + k0 + tx] = f2bf(t[tx][ty + 8 * i]);
}

// ---------------- weight transpose + hi/lo split (R8 proven) ----------------
__global__ __launch_bounds__(256) void wconv_split_kernel(const float* __restrict__ W,
                                                          unsigned short* __restrict__ Wh,
                                                          unsigned short* __restrict__ Wl,
                                                          int K, int N) {
  __shared__ float t[32][33];
  int n0 = blockIdx.x * 32, k0 = blockIdx.y * 32;
  int tx = threadIdx.x & 31, ty = threadIdx.x >> 5;
#pragma unroll
  for (int i = 0; i < 4; i++)
    t[ty + 8 * i][tx] = W[(size_t)(k0 + ty + 8 * i) * N + n0 + tx];
  __syncthreads();
#pragma unroll
  for (int i = 0; i < 4; i++) {
    float w = t[tx][ty + 8 * i];
    unsigned short h = f2bf(w);
    size_t o = (size_t)(n0 + ty + 8 * i) * K + k0 + tx;
    Wh[o] = h;
    Wl[o] = f2bf(w - bf2f(h));
  }
}

// XCD-chunked bijective swizzle (requires gridDim.x*gridDim.y % 8 == 0)
__device__ __forceinline__ void xcd_swz(int& bx, int& by) {
  int bid = blockIdx.y * gridDim.x + blockIdx.x;
  int cpx = (gridDim.x * gridDim.y) >> 3;
  bid = (bid & 7) * cpx + (bid >> 3);
  bx = bid % gridDim.x;
  by = bid / gridDim.x;
}

// ---------------- split-bf16 MFMA GEMM (R8 core) + fused epilogues ----------------
// MODE 0: C=v   1: gelu(v+bias) -> split Ch,Cl   2: C+=v   3: C+=v+bias
template <int MODE>
__global__ __launch_bounds__(256) void gemm_split(const unsigned short* __restrict__ Ah,
                                                  const unsigned short* __restrict__ Al,
                                                  const unsigned short* __restrict__ Bth,
                                                  const unsigned short* __restrict__ Btl,
                                                  float* __restrict__ C,
                                                  unsigned short* __restrict__ Ch,
                                                  unsigned short* __restrict__ Cl,
                                                  const float* __restrict__ bias,
                                                  int M, int Nn, int K) {
  __shared__ __align__(16) unsigned short AsH[128 * 32];
  __shared__ __align__(16) unsigned short AsL[128 * 32];
  __shared__ __align__(16) unsigned short BsH[128 * 32];
  __shared__ __align__(16) unsigned short BsL[128 * 32];
  const int tid = threadIdx.x;
  const int wv = tid >> 6, ln = tid & 63;
  int sbx, sby;
  xcd_swz(sbx, sby);
  const int bm = sby * 128, bn = sbx * 128;

  const size_t aoff0 = (size_t)(bm + 32 * wv + (ln >> 2)) * K + (size_t)((ln & 3) * 8);
  const size_t aoff1 = aoff0 + (size_t)16 * K;
  const size_t boff0 = (size_t)(bn + 32 * wv + (ln >> 2)) * K + (size_t)((ln & 3) * 8);
  const size_t boff1 = boff0 + (size_t)16 * K;
  const int lofs = 1024 * wv + ln * 8;

  const int wm = wv >> 1, wn = wv & 1;
  const int lr = ln & 15, lg = ln >> 4;

  f32x4 acc[4][4];
#pragma unroll
  for (int i = 0; i < 4; i++)
#pragma unroll
    for (int j = 0; j < 4; j++) acc[i][j] = (f32x4){0.f, 0.f, 0.f, 0.f};

  for (int k0 = 0; k0 < K; k0 += 32) {
    short8 rah0 = *(const short8*)(Ah + aoff0 + k0);
    short8 rah1 = *(const short8*)(Ah + aoff1 + k0);
    short8 ral0 = *(const short8*)(Al + aoff0 + k0);
    short8 ral1 = *(const short8*)(Al + aoff1 + k0);
    short8 rbh0 = *(const short8*)(Bth + boff0 + k0);
    short8 rbh1 = *(const short8*)(Bth + boff1 + k0);
    short8 rbl0 = *(const short8*)(Btl + boff0 + k0);
    short8 rbl1 = *(const short8*)(Btl + boff1 + k0);
    __syncthreads();
    *(short8*)(AsH + lofs)       = rah0;
    *(short8*)(AsH + lofs + 512) = rah1;
    *(short8*)(AsL + lofs)       = ral0;
    *(short8*)(AsL + lofs + 512) = ral1;
    *(short8*)(BsH + lofs)       = rbh0;
    *(short8*)(BsH + lofs + 512) = rbh1;
    *(short8*)(BsL + lofs)       = rbl0;
    *(short8*)(BsL + lofs + 512) = rbl1;
    __syncthreads();

    short8 afh[4], afl[4], bwh[4], bwl[4];
#pragma unroll
    for (int i = 0; i < 4; i++) {
      const int ao = (64 * wm + 16 * i + lr) * 32 + 8 * lg;
      afh[i] = *(const short8*)(AsH + ao);
      afl[i] = *(const short8*)(AsL + ao);
    }
#pragma unroll
    for (int j = 0; j < 4; j++) {
      const int bo = (64 * wn + 16 * j + lr) * 32 + 8 * lg;
      bwh[j] = *(const short8*)(BsH + bo);
      bwl[j] = *(const short8*)(BsL + bo);
    }
#pragma unroll
    for (int i = 0; i < 4; i++)
#pragma unroll
      for (int j = 0; j < 4; j++) {
        acc[i][j] = __builtin_amdgcn_mfma_f32_16x16x32_bf16(afh[i], bwh[j], acc[i][j], 0, 0, 0);
        acc[i][j] = __builtin_amdgcn_mfma_f32_16x16x32_bf16(afl[i], bwh[j], acc[i][j], 0, 0, 0);
        acc[i][j] = __builtin_amdgcn_mfma_f32_16x16x32_bf16(afh[i], bwl[j], acc[i][j], 0, 0, 0);
      }
  }

#pragma unroll
  for (int j = 0; j < 4; j++) {
    const int n = bn + 64 * wn + 16 * j + lr;
    const float bb = (MODE == 1 || MODE == 3) ? bias[n] : 0.0f;
#pragma unroll
    for (int i = 0; i < 4; i++) {
#pragma unroll
      for (int rr = 0; rr < 4; rr++) {
        const int m = bm + 64 * wm + 16 * i + 4 * lg + rr;
        float v = acc[i][j][rr];
        const size_t ci = (size_t)m * Nn + n;
        if constexpr (MODE == 0) {
          C[ci] = v;
        } else if constexpr (MODE == 1) {
          v += bb;
          v = 0.5f * v * (1.0f + erff(v * 0.70710678118654752f));
          unsigned short h = f2bf(v);
          Ch[ci] = h;
          Cl[ci] = f2bf(v - bf2f(h));
        } else if constexpr (MODE == 2) {
          C[ci] += v;
        } else {
          C[ci] += v + bb;
        }
      }
    }
  }
}

// ---------------- bf16 MFMA GEMM (R4/R7 core) + fused epilogues ----------------
// MODE 0: C=v (f32)   1: gelu(v+bias) -> bf16 Cu   2: C += rowscale[m]*(v+bias)
template <int MODE>
__global__ __launch_bounds__(256) void gemm_bf16(const unsigned short* __restrict__ A,
                                                 const unsigned short* __restrict__ Bt,
                                                 float* __restrict__ C,
                                                 unsigned short* __restrict__ Cu,
                                                 const float* __restrict__ bias,
                                                 const float* __restrict__ rowscale,
                                                 int M, int Nn, int K) {
  __shared__ __align__(16) unsigned short As[128 * 32];
  __shared__ __align__(16) unsigned short Bs[128 * 32];
  const int tid = threadIdx.x;
  const int wv = tid >> 6, ln = tid & 63;
  int sbx, sby;
  xcd_swz(sbx, sby);
  const int bm = sby * 128, bn = sbx * 128;

  const size_t aoff0 = (size_t)(bm + 32 * wv + (ln >> 2)) * K + (size_t)((ln & 3) * 8);
  const size_t aoff1 = aoff0 + (size_t)16 * K;
  const size_t boff0 = (size_t)(bn + 32 * wv + (ln >> 2)) * K + (size_t)((ln & 3) * 8);
  const size_t boff1 = boff0 + (size_t)16 * K;
  const int lofs = 1024 * wv + ln * 8;

  const int wm = wv >> 1, wn = wv & 1;
  const int lr = ln & 15, lg = ln >> 4;

  f32x4 acc[4][4];
#pragma unroll
  for (int i = 0; i < 4; i++)
#pragma unroll
    for (int j = 0; j < 4; j++) acc[i][j] = (f32x4){0.f, 0.f, 0.f, 0.f};

  for (int k0 = 0; k0 < K; k0 += 32) {
    short8 ra0 = *(const short8*)(A + aoff0 + k0);
    short8 ra1 = *(const short8*)(A + aoff1 + k0);
    short8 rb0 = *(const short8*)(Bt + boff0 + k0);
    short8 rb1 = *(const short8*)(Bt + boff1 + k0);
    __syncthreads();
    *(short8*)(As + lofs)       = ra0;
    *(short8*)(As + lofs + 512) = ra1;
    *(short8*)(Bs + lofs)       = rb0;
    *(short8*)(Bs + lofs + 512) = rb1;
    __syncthreads();

    short8 af[4], bw[4];
#pragma unroll
    for (int i = 0; i < 4; i++)
      af[i] = *(const short8*)(As + ((64 * wm + 16 * i + lr) * 32 + 8 * lg));
#pragma unroll
    for (int j = 0; j < 4; j++)
      bw[j] = *(const short8*)(Bs + ((64 * wn + 16 * j + lr) * 32 + 8 * lg));
#pragma unroll
    for (int i = 0; i < 4; i++)
#pragma unroll
      for (int j = 0; j < 4; j++)
        acc[i][j] = __builtin_amdgcn_mfma_f32_16x16x32_bf16(af[i], bw[j], acc[i][j], 0, 0, 0);
  }

#pragma unroll
  for (int j = 0; j < 4; j++) {
    const int n = bn + 64 * wn + 16 * j + lr;
    const float bb = (MODE != 0) ? bias[n] : 0.0f;
#pragma unroll
    for (int i = 0; i < 4; i++) {
#pragma unroll
      for (int r = 0; r < 4; r++) {
        const int m = bm + 64 * wm + 16 * i + 4 * lg + r;
        float v = acc[i][j][r];
        const size_t ci = (size_t)m * Nn + n;
        if constexpr (MODE == 0) {
          C[ci] = v;
        } else if constexpr (MODE == 1) {
          v += bb;
          v = 0.5f * v * (1.0f + erff(v * 0.70710678118654752f));
          Cu[ci] = f2bf(v);
        } else {
          C[ci] += rowscale[m] * (v + bb);
        }
      }
    }
  }
}

// ---------------- router (R0 proven) ----------------
__global__ __launch_bounds__(64) void router_kernel(const float* __restrict__ x,
                                                    const float* __restrict__ rw,
                                                    float* __restrict__ maskT) {
  int n = blockIdx.x, lane = threadIdx.x;
  const float* xr = x + (size_t)n * CDIM;
  float acc[NEXP] = {};
  for (int i = 0; i < CDIM / 64; i++) {
    int c = lane + 64 * i;
    float xv = xr[c];
    const float* r = rw + (size_t)c * NEXP;
#pragma unroll
    for (int e = 0; e < NEXP; e++) acc[e] += xv * r[e];
  }
  for (int m = 32; m >= 1; m >>= 1)
#pragma unroll
    for (int e = 0; e < NEXP; e++) acc[e] += __shfl_xor(acc[e], m);
  if (lane == 0) {
    float mx = acc[0];
#pragma unroll
    for (int e = 1; e < NEXP; e++) mx = fmaxf(mx, acc[e]);
    float p[NEXP];
#pragma unroll
    for (int e = 0; e < NEXP; e++) p[e] = expf(acc[e] - mx);
    int i1 = 0;
#pragma unroll
    for (int e = 1; e < NEXP; e++) if (p[e] > p[i1]) i1 = e;
    int i2 = (i1 == 0) ? 1 : 0;
#pragma unroll
    for (int e = 0; e < NEXP; e++) if (e != i1 && p[e] > p[i2]) i2 = e;
    float denom = p[i1] + p[i2];
    float w1 = p[i1] / denom, w2 = p[i2] / denom;
#pragma unroll
    for (int e = 0; e < NEXP; e++) maskT[(size_t)e * NTOK + n] = 0.0f;
    maskT[(size_t)i1 * NTOK + n] = w1;
    maskT[(size_t)i2 * NTOK + n] = w2;
  }
}

extern "C" void kernel_launch(void* const* d_in, const int* in_sizes, int n_in,
                              void* d_out, int out_size, void* d_ws, size_t ws_size,
                              hipStream_t stream) {
  const int*   idx      = (const int*)d_in[0];
  const float* tok_emb  = (const float*)d_in[1];
  const float* ln1_g    = (const float*)d_in[2];
  const float* ln1_b    = (const float*)d_in[3];
  const float* ln2_g    = (const float*)d_in[4];
  const float* ln2_b    = (const float*)d_in[5];
  const float* qkv_w    = (const float*)d_in[6];
  const float* proj_w   = (const float*)d_in[7];
  const float* ff_w1    = (const float*)d_in[8];
  const float* ff_b1    = (const float*)d_in[9];
  const float* ff_w2    = (const float*)d_in[10];
  const float* ff_b2    = (const float*)d_in[11];
  const float* router_w = (const float*)d_in[12];
  const float* exp_w1   = (const float*)d_in[13];
  const float* exp_b1   = (const float*)d_in[14];
  const float* exp_w2   = (const float*)d_in[15];
  const float* exp_b2   = (const float*)d_in[16];
  const float* lnf_g    = (const float*)d_in[17];
  const float* lnf_b    = (const float*)d_in[18];
  const float* head_w   = (const float*)d_in[19];
  float* out = (float*)d_out;

  // ---- workspace layout (same as R13, ~143.5 MB) ----
  const size_t NC = (size_t)NTOK * CDIM;
  char* w = (char*)d_ws;
  float* x  = (float*)w;                 w += NC * 4;
  unsigned short* S1 = (unsigned short*)w; w += NC * 4;
  float* Q  = (float*)w;                 w += (size_t)NTOK * C3 * 4;
  float* C3r = (float*)w;                w += NC * 4;
  unsigned short* WS = (unsigned short*)w; w += NC * 4;
  unsigned short* EX = (unsigned short*)w; w += NC * 6;
  float* maskT = (float*)w;              w += (size_t)NEXP * NTOK * 4;
  float* ct = (float*)w;                 w += (size_t)TSEQ * 32 * 4;
  float* st = (float*)w;                 w += (size_t)TSEQ * 32 * 4;

  // trunk aliases
  unsigned short* xh = S1;
  unsigned short* xl = S1 + NC;
  unsigned short* Wh = WS;
  unsigned short* Wl = WS + NC;
  float* qkvf = Q;
  // attention-phase aliases
  unsigned short* Qh_s = S1;
  unsigned short* Qm_s = S1 + NC;
  unsigned short* Ql_s = EX;
  unsigned short* Kh_s = (unsigned short*)C3r;
  unsigned short* Km_s = (unsigned short*)C3r + NC;
  unsigned short* Kl_s = EX + NC;
  unsigned short* Vth_s = WS;
  unsigned short* Vtm_s = WS + NC;
  unsigned short* Vtl_s = EX + 2 * NC;
  unsigned short* ath = (unsigned short*)Q;            // flash split out (qkvf dead)
  unsigned short* atl = (unsigned short*)Q + NC;
  // FF aliases
  unsigned short* hh = (unsigned short*)Q;
  unsigned short* hl = (unsigned short*)Q + (size_t)NTOK * FFDIM;
  // MoE aliases
  unsigned short* x_bf    = S1;
  unsigned short* hmoe_bf = S1 + NC;
  float* moe_out  = x;
  unsigned short* wt_s = WS;
  // head aliases
  unsigned short* xn_bf   = S1;
  unsigned short* wt_head = (unsigned short*)Q;

  embed_kernel<<<NTOK, 256, 0, stream>>>(idx, tok_emb, x);
  rope_table_kernel<<<TSEQ, 32, 0, stream>>>(ct, st);

  for (int l = 0; l < LAYERS; l++) {
    // --- attention sublayer ---
    ln_split_kernel<<<NTOK, 256, 0, stream>>>(x, xh, xl, ln1_g + l * CDIM, ln1_b + l * CDIM);
    wconv_split_kernel<<<dim3(C3 / 32, CDIM / 32), 256, 0, stream>>>(
        qkv_w + (size_t)l * CDIM * C3, Wh, Wl, CDIM, C3);
    gemm_split<0><<<dim3(C3 / 128, NTOK / 128), 256, 0, stream>>>(
        xh, xl, Wh, Wl, qkvf, nullptr, nullptr, nullptr, NTOK, C3, CDIM);
    qkv_prep_kernel<<<dim3(TSEQ / 64, HEADS, 8), 256, 0, stream>>>(
        qkvf, ct, st, Qh_s, Qm_s, Ql_s, Kh_s, Km_s, Kl_s, Vth_s, Vtm_s, Vtl_s);
    flash_attn_kernel<<<dim3(TSEQ / 64, HEADS, 8), 256, 0, stream>>>(
        Qh_s, Qm_s, Ql_s, Kh_s, Km_s, Kl_s, Vth_s, Vtm_s, Vtl_s, ath, atl);
    wconv_split_kernel<<<dim3(CDIM / 32, CDIM / 32), 256, 0, stream>>>(
        proj_w + (size_t)l * CDIM * CDIM, Wh, Wl, CDIM, CDIM);
    gemm_split<2><<<dim3(CDIM / 128, NTOK / 128), 256, 0, stream>>>(
        ath, atl, Wh, Wl, x, nullptr, nullptr, nullptr, NTOK, CDIM, CDIM);
    // --- FF sublayer ---
    ln_split_kernel<<<NTOK, 256, 0, stream>>>(x, xh, xl, ln2_g + l * CDIM, ln2_b + l * CDIM);
    wconv_split_kernel<<<dim3(FFDIM / 32, CDIM / 32), 256, 0, stream>>>(
        ff_w1 + (size_t)l * CDIM * FFDIM, Wh, Wl, CDIM, FFDIM);
    gemm_split<1><<<dim3(FFDIM / 128, NTOK / 128), 256, 0, stream>>>(
        xh, xl, Wh, Wl, nullptr, hh, hl, ff_b1 + (size_t)l * FFDIM, NTOK, FFDIM, CDIM);
    wconv_split_kernel<<<dim3(CDIM / 32, FFDIM / 32), 256, 0, stream>>>(
        ff_w2 + (size_t)l * FFDIM * CDIM, Wh, Wl, FFDIM, CDIM);
    gemm_split<3><<<dim3(CDIM / 128, NTOK / 128), 256, 0, stream>>>(
        hh, hl, Wh, Wl, x, nullptr, nullptr, ff_b2 + (size_t)l * CDIM, NTOK, CDIM, FFDIM);
  }

  // --- router on trunk x, then MoE bf16 (fused epilogues) ---
  router_kernel<<<NTOK, 64, 0, stream>>>(x, router_w, maskT);
  cvt_bf16_kernel<<<(NC / 4) / 256, 256, 0, stream>>>(x, x_bf);
  hipMemsetAsync(moe_out, 0, NC * sizeof(float), stream);
  for (int e = 0; e < NEXP; e++) {
    wconv_t_kernel<<<dim3(DEXP / 32, CDIM / 32), 256, 0, stream>>>(
        exp_w1 + (size_t)e * CDIM * DEXP, wt_s, CDIM, DEXP);
    gemm_bf16<1><<<dim3(DEXP / 128, NTOK / 128), 256, 0, stream>>>(
        x_bf, wt_s, nullptr, hmoe_bf, exp_b1 + (size_t)e * DEXP, nullptr, NTOK, DEXP, CDIM);
    wconv_t_kernel<<<dim3(CDIM / 32, DEXP / 32), 256, 0, stream>>>(
        exp_w2 + (size_t)e * DEXP * CDIM, wt_s, DEXP, CDIM);
    gemm_bf16<2><<<dim3(CDIM / 128, NTOK / 128), 256, 0, stream>>>(
        hmoe_bf, wt_s, moe_out, nullptr, exp_b2 + (size_t)e * CDIM,
        maskT + (size_t)e * NTOK, NTOK, CDIM, DEXP);
  }

  // --- head ---
  ln_bf16_kernel<<<NTOK, 256, 0, stream>>>(moe_out, xn_bf, lnf_g, lnf_b);
  wconv_t_kernel<<<dim3(VOCAB / 32, CDIM / 32), 256, 0, stream>>>(head_w, wt_head, CDIM, VOCAB);
  gemm_bf16<0><<<dim3(VOCAB / 128, NTOK / 128), 256, 0, stream>>>(
      xn_bf, wt_head, out, nullptr, nullptr, nullptr, NTOK, VOCAB, CDIM);
}